// Round 4
// baseline (369.478 us; speedup 1.0000x reference)
//
#include <hip/hip_runtime.h>

// Problem constants
#define NB    2048     // users / segments
#define NP    16384    // posts
#define LL    50       // tokens per post
#define DD    300      // embedding dim
#define DP    320      // d padded to multiple of 32 (MFMA K tiles)
#define TP    52       // t rows incl. zero pad (48 outputs + 4 shift overhang)
#define NTOT  300      // total filters (100 per conv)
#define NPADF 320      // filters padded to 20 N-tiles of 16
#define INFEAT 768
#define HID2  128
#define UPB   4        // users per conv block
#define FCM   16       // users per fc block

typedef short v8s __attribute__((ext_vector_type(8)));
typedef float v4f __attribute__((ext_vector_type(4)));

__device__ __forceinline__ unsigned short f2bf(float f) {
    union { float f; unsigned u; } v; v.f = f;
    return (unsigned short)((v.u + 0x7FFF + ((v.u >> 16) & 1)) >> 16);  // RNE
}
__device__ __forceinline__ float bf2f(unsigned short u) {
    union { unsigned u; float f; } v; v.u = ((unsigned)u) << 16; return v.f;
}
__device__ __forceinline__ int lower_bound_i(const int* __restrict__ a, int n, int v) {
    int lo = 0, hi = n;
    while (lo < hi) { int mid = (lo + hi) >> 1; if (a[mid] < v) lo = mid + 1; else hi = mid; }
    return lo;
}

// async global->LDS 16B copy: LDS dest = (uniform base) + lane*16, global src per-lane.
// Both sides linear in identical chunk order (no swizzle on either side).
__device__ __forceinline__ void async_copy16(const void* g, void* l) {
    __builtin_amdgcn_global_load_lds(
        (const __attribute__((address_space(1))) unsigned int*)g,
        (__attribute__((address_space(3))) unsigned int*)l, 16, 0, 0);
}

// ---- generic fp32 -> bf16 (used for emb table and fc_w1) ----
__global__ void emb_cvt(const float* __restrict__ in, unsigned short* __restrict__ out, int n4) {
    int i = blockIdx.x * blockDim.x + threadIdx.x;
    if (i >= n4) return;
    float4 v = ((const float4*)in)[i];
    ushort4 o; o.x = f2bf(v.x); o.y = f2bf(v.y); o.z = f2bf(v.z); o.w = f2bf(v.w);
    ((ushort4*)out)[i] = o;
}

// ---- conv weights -> bf16 fragment-order W5f[step=kt*5+s][nt][lane][8] + bias_all ----
__global__ void prep_w(const float* __restrict__ w3, const float* __restrict__ w4,
                       const float* __restrict__ w5,
                       const float* __restrict__ b3, const float* __restrict__ b4,
                       const float* __restrict__ b5,
                       unsigned short* __restrict__ W5f, float* __restrict__ bias_all) {
    int idx = blockIdx.x * blockDim.x + threadIdx.x;
    if (idx < NPADF) {
        float bv = 0.f;
        if (idx < 100) bv = b3[idx];
        else if (idx < 200) bv = b4[idx - 100];
        else if (idx < 300) bv = b5[idx - 200];
        bias_all[idx] = bv;
    }
    if (idx >= 10 * 5 * 20 * 512) return;
    int j    = idx & 7;
    int lane = (idx >> 3) & 63;
    int rest = idx >> 9;            // kt*100 + s*20 + nt
    int nt = rest % 20;
    int s  = (rest / 20) % 5;
    int kt = rest / 100;
    int col = lane & 15, quad = lane >> 4;
    int nf = nt * 16 + col;
    int d  = kt * 32 + quad * 8 + j;
    float v = 0.f;
    if (nf < NTOT && d < DD) {
        int cls = nf / 100, f = nf % 100, K = cls + 3;
        if (s < K) {
            const float* w = (cls == 0) ? w3 : (cls == 1) ? w4 : w5;
            v = w[(f * DD + d) * K + s];
        }
    }
    W5f[idx] = f2bf(v);
}

// ---- ragged segment-mean -> bf16 hist[b][52][320], vectorized ushort4 gather ----
#define PCHUNK 32
__global__ __launch_bounds__(512, 1) void gather_kernel(
    const int* __restrict__ hist_tokens, const int* __restrict__ seg,
    const unsigned short* __restrict__ embb, unsigned short* __restrict__ histb)
{
    __shared__ int tokoff[PCHUNK * LL];
    const int b = blockIdx.x, tid = threadIdx.x;
    const int lo = lower_bound_i(seg, NP, b);
    const int hi = lower_bound_i(seg, NP, b + 1);
    const float inv = 1.0f / fmaxf((float)(hi - lo), 1.0f);

    int toff[8], doff[8];
    #pragma unroll
    for (int j = 0; j < 8; ++j) {
        int idx = tid + 512 * j;
        if (idx < 3750) { toff[j] = idx / 75; doff[j] = (idx % 75) * 4; }
        else            { toff[j] = 0;        doff[j] = 0; }
    }
    const bool has8 = (tid < 166);

    float4 acc[8];
    #pragma unroll
    for (int j = 0; j < 8; ++j) acc[j] = make_float4(0.f, 0.f, 0.f, 0.f);

    for (int p0 = lo; p0 < hi; p0 += PCHUNK) {
        const int pc = min(PCHUNK, hi - p0);
        __syncthreads();
        for (int j = tid; j < pc * LL; j += 512)
            tokoff[j] = hist_tokens[p0 * LL + j] * DD;
        __syncthreads();
        for (int pp = 0; pp < pc; ++pp) {
            const int* tr = tokoff + pp * LL;
            #pragma unroll
            for (int j = 0; j < 7; ++j) {
                const ushort4 v = *(const ushort4*)(embb + tr[toff[j]] + doff[j]);
                acc[j].x += bf2f(v.x); acc[j].y += bf2f(v.y);
                acc[j].z += bf2f(v.z); acc[j].w += bf2f(v.w);
            }
            if (has8) {
                const ushort4 v = *(const ushort4*)(embb + tr[toff[7]] + doff[7]);
                acc[7].x += bf2f(v.x); acc[7].y += bf2f(v.y);
                acc[7].z += bf2f(v.z); acc[7].w += bf2f(v.w);
            }
        }
    }

    unsigned short* hb = histb + (size_t)b * TP * DP;
    #pragma unroll
    for (int j = 0; j < 8; ++j) {
        if (j < 7 || has8) {
            ushort4 o;
            o.x = f2bf(acc[j].x * inv); o.y = f2bf(acc[j].y * inv);
            o.z = f2bf(acc[j].z * inv); o.w = f2bf(acc[j].w * inv);
            *(ushort4*)(hb + toff[j] * DP + doff[j]) = o;
        }
    }
    for (int i = tid; i < 640 + 1000; i += 512) {
        int t, d;
        if (i < 640) { t = 50 + i / 320; d = i % 320; }
        else         { int j = i - 640; t = j / 20; d = 300 + j % 20; }
        hb[t * DP + d] = 0;
    }
}

// ---- conv: 4 users/block, 12 waves = 4 users x 3 n-groups {0-6,7-13,14-18}.
//      Each wave: all 3 m-tiles x its n-group -> acc[3][7] (84 AGPR), 3 waves/SIMD.
//      B staged via async global_load_lds into DOUBLE-buffered sB. One barrier
//      per step; its implicit vmcnt(0) is the per-wave DMA completion handshake.
//      Race-free: DMA(step+1) issued after bar(step) (buffer freed), drained by
//      bar(step+1) before any read. sched_barrier(0) pins the DMA issues (and
//      s==4 A-prefetch) ABOVE the compute batch so the compiler cannot sink
//      them to the bottom of the interval (which exposes the full DMA latency
//      at the next barrier drain -- the round-3 regression). ----
__global__ __launch_bounds__(768, 3) void conv_kernel(
    const unsigned short* __restrict__ histb, const unsigned short* __restrict__ W5f,
    const float* __restrict__ bias_all,
    const float* __restrict__ hist_w, const float* __restrict__ hist_b,
    float* __restrict__ out)
{
    __shared__ __align__(16) unsigned short sA[UPB * 52 * 40];   // 16,640 B
    __shared__ __align__(16) unsigned short sB[2][19 * 512];     // 38,912 B
    __shared__ __align__(16) float fpool[UPB * NPADF];           //  5,120 B

    const int b = blockIdx.x, tid = threadIdx.x;
    const int wave = tid >> 6, lane = tid & 63;
    const int col = lane & 15, quad = lane >> 4;
    const int u = wave & 3, g = wave >> 2;      // user 0..3, n-group 0..2
    const int base = (g == 2) ? 14 : g * 7;     // first tile of group
    const int cnt  = (g == 2) ? 5  : 7;         // live tiles in group

    const unsigned short* hbase = histb + (size_t)(b * UPB) * TP * DP;

    // A staging chunk decode (832 chunks: 4 users x 52 rows x 4 ch of 8 ushorts)
    const int c0 = tid;
    const int a0_uu = c0 / 208, a0_r = c0 % 208;
    const int a0_row = a0_r >> 2, a0_ch = a0_r & 3;
    const int c1 = tid + 768;
    const int a1_uu = c1 / 208, a1_r = c1 % 208;
    const int a1_row = a1_r >> 2, a1_ch = a1_r & 3;
    const bool hasA1 = (tid < 64);              // 832 - 768

    v4f acc[3][7];
    #pragma unroll
    for (int m = 0; m < 3; ++m)
        #pragma unroll
        for (int j = 0; j < 7; ++j)
            acc[m][j] = (v4f){0.f, 0.f, 0.f, 0.f};

    // ---- prologue: DMA B(step=0) -> sB[0]; load A(kt=0) into regs ----
    v8s a0v = {}, a1v = {};
    {
        const int cb0 = wave, cb1 = wave + 12;
        async_copy16(W5f + (size_t)cb0 * 512 + lane * 8, sB[0] + cb0 * 512);
        if (cb1 < 19)
            async_copy16(W5f + (size_t)cb1 * 512 + lane * 8, sB[0] + cb1 * 512);
    }
    a0v = *(const v8s*)(hbase + (size_t)a0_uu * TP * DP + a0_row * DP + a0_ch * 8);
    if (hasA1)
        a1v = *(const v8s*)(hbase + (size_t)a1_uu * TP * DP + a1_row * DP + a1_ch * 8);

    for (int kt = 0; kt < 10; ++kt) {
        #pragma unroll
        for (int s = 0; s < 5; ++s) {
            const int step = kt * 5 + s;
            const int lo   = (s == 3) ? 6 : (s == 4) ? 12 : 0;   // live tile range [lo,19)

            // bar(i): implicit vmcnt(0) drains this wave's DMA (issued step i-1)
            // and A-reg loads; after s_barrier all waves' staging is visible.
            __syncthreads();
            if (s == 0) {
                *(v8s*)(sA + (a0_uu * 52 + a0_row) * 40 + a0_ch * 8) = a0v;
                if (hasA1) *(v8s*)(sA + (a1_uu * 52 + a1_row) * 40 + a1_ch * 8) = a1v;
                __syncthreads();               // A visible
            }

            // -- issue next step's B DMA into the other buffer (EARLY) --
            if (step < 49) {
                const int sn  = (s == 4) ? 0 : s + 1;
                const int lon = (sn == 3) ? 6 : (sn == 4) ? 12 : 0;
                const int ntl = 19 - lon;
                const unsigned short* gb = W5f + (size_t)(step + 1) * 10240 + lon * 512;
                unsigned short* sbn = sB[(step + 1) & 1] + lon * 512;
                const int cb0 = wave, cb1 = wave + 12;
                if (cb0 < ntl)
                    async_copy16(gb + (size_t)cb0 * 512 + lane * 8, sbn + cb0 * 512);
                if (cb1 < ntl)
                    async_copy16(gb + (size_t)cb1 * 512 + lane * 8, sbn + cb1 * 512);
            }
            // -- prefetch next A kt into regs (consumed at next s==0 after bar) --
            if (s == 4 && kt < 9) {
                const int ko = (kt + 1) * 32;
                a0v = *(const v8s*)(hbase + (size_t)a0_uu * TP * DP + a0_row * DP + ko + a0_ch * 8);
                if (hasA1)
                    a1v = *(const v8s*)(hbase + (size_t)a1_uu * TP * DP + a1_row * DP + ko + a1_ch * 8);
            }
            // Pin: everything above must be ISSUED before the compute batch below.
            // Without this the compiler sinks the DMA issues to the interval tail,
            // exposing the full DMA latency at the next barrier's vmcnt(0) drain.
            __builtin_amdgcn_sched_barrier(0);

            // -- compute: 3 A frags + up to 7 B frags, 3 MFMA per B frag --
            const unsigned short* Bbuf = sB[step & 1];
            const unsigned short* Arow = sA + (u * 52 + col + s) * 40 + quad * 8;
            const v8s am0 = *(const v8s*)(Arow);
            const v8s am1 = *(const v8s*)(Arow + 640);    // +16 rows * 40
            const v8s am2 = *(const v8s*)(Arow + 1280);   // +32 rows * 40
            #pragma unroll
            for (int j = 0; j < 7; ++j) {
                const int t = base + j;
                if (j < cnt && t >= lo) {
                    const v8s bf = *(const v8s*)(Bbuf + t * 512 + lane * 8);
                    acc[0][j] = __builtin_amdgcn_mfma_f32_16x16x32_bf16(am0, bf, acc[0][j], 0, 0, 0);
                    acc[1][j] = __builtin_amdgcn_mfma_f32_16x16x32_bf16(am1, bf, acc[1][j], 0, 0, 0);
                    acc[2][j] = __builtin_amdgcn_mfma_f32_16x16x32_bf16(am2, bf, acc[2][j], 0, 0, 0);
                }
            }
        }
    }

    // maxpool + bias + relu -> fpool (wave-local: each wave owns all m for its tiles)
    #pragma unroll
    for (int j = 0; j < 7; ++j) {
        if (j < cnt) {
            const int nf = (base + j) * 16 + col;
            const int Tout = 48 - nf / 100;        // 48/47/46 per class
            float mx = -1e30f;
            #pragma unroll
            for (int m = 0; m < 3; ++m)
                #pragma unroll
                for (int r = 0; r < 4; ++r) {
                    const int t = m * 16 + quad * 4 + r;
                    if (t < Tout) mx = fmaxf(mx, acc[m][j][r]);
                }
            mx = fmaxf(mx, __shfl_xor(mx, 16, 64));
            mx = fmaxf(mx, __shfl_xor(mx, 32, 64));
            if (quad == 0 && nf < NTOT)
                fpool[u * NPADF + nf] = fmaxf(0.f, mx + bias_all[nf]);
        }
    }
    __syncthreads();

    // rec = fpool @ hist_w.T + hist_b
    if (tid < UPB * 64) {
        const int uu = tid >> 6, o = tid & 63;
        const float4* fw = (const float4*)(hist_w + o * NTOT);
        const float4* fp = (const float4*)(fpool + uu * NPADF);
        float sum = 0.f;
        #pragma unroll
        for (int q = 0; q < NTOT / 4; ++q) {
            float4 aa = fp[q], ww = fw[q];
            sum += aa.x * ww.x + aa.y * ww.y + aa.z * ww.z + aa.w * ww.w;
        }
        out[(b * UPB + uu) * 64 + o] = sum + hist_b[o];
    }
}

// ---- fc via MFMA: h = relu(x[root] @ w1b.T + b1) ; out += h @ w2.T + b2 ----
__global__ __launch_bounds__(256, 1) void fc_mfma(
    const float* __restrict__ x, const int* __restrict__ rootindex,
    const unsigned short* __restrict__ w1b, const float* __restrict__ b1,
    const float* __restrict__ w2, const float* __restrict__ b2,
    float* __restrict__ out)
{
    __shared__ __align__(16) unsigned short sA[FCM * 72];   // 16 rows x 64k (pad 72)
    __shared__ __align__(16) float hl[FCM * 132];           // h tile, stride 132
    __shared__ __align__(16) float w2l[64 * 129];           // w2 staged, stride 129
    __shared__ int roots[FCM];

    const int b = blockIdx.x, tid = threadIdx.x;
    if (tid < FCM) roots[tid] = rootindex[b * FCM + tid];
    for (int i = tid; i < 64 * HID2; i += 256)
        w2l[(i >> 7) * 129 + (i & 127)] = w2[i];
    __syncthreads();

    const int wave = tid >> 6, lane = tid & 63;
    const int col = lane & 15, quad = lane >> 4;

    v4f acc[2];
    acc[0] = (v4f){0.f, 0.f, 0.f, 0.f};
    acc[1] = (v4f){0.f, 0.f, 0.f, 0.f};

    const int r_st = tid >> 4, q_st = tid & 15;

    for (int kt = 0; kt < 12; ++kt) {
        __syncthreads();
        float4 v = *(const float4*)(x + (size_t)roots[r_st] * INFEAT + kt * 64 + q_st * 4);
        ushort4 o; o.x = f2bf(v.x); o.y = f2bf(v.y); o.z = f2bf(v.z); o.w = f2bf(v.w);
        *(ushort4*)(sA + r_st * 72 + q_st * 4) = o;
        __syncthreads();
        #pragma unroll
        for (int kc = 0; kc < 2; ++kc) {
            const v8s a = *(const v8s*)(sA + col * 72 + kc * 32 + quad * 8);
            #pragma unroll
            for (int n = 0; n < 2; ++n) {
                const int nf = (wave * 2 + n) * 16 + col;
                const v8s bfr = *(const v8s*)(w1b + (size_t)nf * INFEAT + kt * 64 + kc * 32 + quad * 8);
                acc[n] = __builtin_amdgcn_mfma_f32_16x16x32_bf16(a, bfr, acc[n], 0, 0, 0);
            }
        }
    }

    #pragma unroll
    for (int nt = 0; nt < 2; ++nt) {
        const int n = (wave * 2 + nt) * 16 + col;
        const float bv = b1[n];
        #pragma unroll
        for (int r = 0; r < 4; ++r)
            hl[(quad * 4 + r) * 132 + n] = fmaxf(acc[nt][r] + bv, 0.f);
    }
    __syncthreads();

    {
        const int o = tid & 63, ug = tid >> 6;
        const float b2v = b2[o];
        const float* wrow = w2l + o * 129;
        #pragma unroll
        for (int i = 0; i < 4; ++i) {
            const int u = ug * 4 + i;
            const float* hrow = hl + u * 132;
            float s = 0.f;
            #pragma unroll 16
            for (int k = 0; k < HID2; ++k) s += hrow[k] * wrow[k];
            out[(b * FCM + u) * 64 + o] += s + b2v;
        }
    }
}

extern "C" void kernel_launch(void* const* d_in, const int* in_sizes, int n_in,
                              void* d_out, int out_size, void* d_ws, size_t ws_size,
                              hipStream_t stream) {
    const float* x        = (const float*)d_in[0];
    const int*   rootidx  = (const int*)d_in[1];
    const int*   hist_tok = (const int*)d_in[2];
    const int*   seg      = (const int*)d_in[3];
    const float* emb      = (const float*)d_in[4];
    const float* w3       = (const float*)d_in[5];
    const float* cb3      = (const float*)d_in[6];
    const float* w4       = (const float*)d_in[7];
    const float* cb4      = (const float*)d_in[8];
    const float* w5       = (const float*)d_in[9];
    const float* cb5      = (const float*)d_in[10];
    const float* hist_w   = (const float*)d_in[11];
    const float* hist_b   = (const float*)d_in[12];
    const float* fw1      = (const float*)d_in[13];
    const float* fb1      = (const float*)d_in[14];
    const float* fw2      = (const float*)d_in[15];
    const float* fb2      = (const float*)d_in[16];
    float* out = (float*)d_out;

    // workspace layout (bytes)
    char* ws = (char*)d_ws;
    unsigned short* emb_bf  = (unsigned short*)(ws);                    // 30,000,000 B
    unsigned short* hist_bf = (unsigned short*)(ws + 30000000);         // 68,157,440 B
    unsigned short* W5f     = (unsigned short*)(ws + 98157440);         //  1,024,000 B
    float*          bias_all= (float*)(ws + 99181440);                  //      1,280 B
    unsigned short* w1b     = (unsigned short*)(ws + 99182720);         //    196,608 B

    emb_cvt<<<(50000 * DD / 4 + 255) / 256, 256, 0, stream>>>(emb, emb_bf, 50000 * DD / 4);
    emb_cvt<<<(HID2 * INFEAT / 4 + 255) / 256, 256, 0, stream>>>(fw1, w1b, HID2 * INFEAT / 4);
    prep_w<<<(10 * 5 * 20 * 512 + 255) / 256, 256, 0, stream>>>(w3, w4, w5, cb3, cb4, cb5, W5f, bias_all);
    gather_kernel<<<NB, 512, 0, stream>>>(hist_tok, seg, emb_bf, hist_bf);
    conv_kernel<<<NB / UPB, 768, 0, stream>>>(hist_bf, W5f, bias_all, hist_w, hist_b, out);
    fc_mfma<<<NB / FCM, 256, 0, stream>>>(x, rootidx, w1b, fb1, fw2, fb2, out);
}

// Round 5
// 347.972 us; speedup vs baseline: 1.0618x; 1.0618x over previous
//
#include <hip/hip_runtime.h>

// Problem constants
#define NB    2048     // users / segments
#define NP    16384    // posts
#define LL    50       // tokens per post
#define DD    300      // embedding dim
#define DP    320      // d padded to multiple of 32 (MFMA K tiles)
#define TP    52       // t rows incl. zero pad (48 outputs + 4 shift overhang)
#define NTOT  300      // total filters (100 per conv)
#define NPADF 320      // filters padded to 20 N-tiles of 16
#define INFEAT 768
#define HID2  128
#define UPB   4        // users per conv block
#define FCM   16       // users per fc block
#define LDA   328      // sA row stride in shorts (320 + 8 pad: 656B = 4-bank skew)

typedef short v8s __attribute__((ext_vector_type(8)));
typedef float v4f __attribute__((ext_vector_type(4)));

__device__ __forceinline__ unsigned short f2bf(float f) {
    union { float f; unsigned u; } v; v.f = f;
    return (unsigned short)((v.u + 0x7FFF + ((v.u >> 16) & 1)) >> 16);  // RNE
}
__device__ __forceinline__ float bf2f(unsigned short u) {
    union { unsigned u; float f; } v; v.u = ((unsigned)u) << 16; return v.f;
}
__device__ __forceinline__ int lower_bound_i(const int* __restrict__ a, int n, int v) {
    int lo = 0, hi = n;
    while (lo < hi) { int mid = (lo + hi) >> 1; if (a[mid] < v) lo = mid + 1; else hi = mid; }
    return lo;
}

// ---- generic fp32 -> bf16 (used for emb table and fc_w1) ----
__global__ void emb_cvt(const float* __restrict__ in, unsigned short* __restrict__ out, int n4) {
    int i = blockIdx.x * blockDim.x + threadIdx.x;
    if (i >= n4) return;
    float4 v = ((const float4*)in)[i];
    ushort4 o; o.x = f2bf(v.x); o.y = f2bf(v.y); o.z = f2bf(v.z); o.w = f2bf(v.w);
    ((ushort4*)out)[i] = o;
}

// ---- conv weights -> bf16 fragment-order W5f[step=kt*5+s][nt][lane][8] + bias_all ----
__global__ void prep_w(const float* __restrict__ w3, const float* __restrict__ w4,
                       const float* __restrict__ w5,
                       const float* __restrict__ b3, const float* __restrict__ b4,
                       const float* __restrict__ b5,
                       unsigned short* __restrict__ W5f, float* __restrict__ bias_all) {
    int idx = blockIdx.x * blockDim.x + threadIdx.x;
    if (idx < NPADF) {
        float bv = 0.f;
        if (idx < 100) bv = b3[idx];
        else if (idx < 200) bv = b4[idx - 100];
        else if (idx < 300) bv = b5[idx - 200];
        bias_all[idx] = bv;
    }
    if (idx >= 10 * 5 * 20 * 512) return;
    int j    = idx & 7;
    int lane = (idx >> 3) & 63;
    int rest = idx >> 9;            // kt*100 + s*20 + nt
    int nt = rest % 20;
    int s  = (rest / 20) % 5;
    int kt = rest / 100;
    int col = lane & 15, quad = lane >> 4;
    int nf = nt * 16 + col;
    int d  = kt * 32 + quad * 8 + j;
    float v = 0.f;
    if (nf < NTOT && d < DD) {
        int cls = nf / 100, f = nf % 100, K = cls + 3;
        if (s < K) {
            const float* w = (cls == 0) ? w3 : (cls == 1) ? w4 : w5;
            v = w[(f * DD + d) * K + s];
        }
    }
    W5f[idx] = f2bf(v);
}

// ---- ragged segment-mean -> bf16 hist[b][52][320], vectorized ushort4 gather ----
#define PCHUNK 32
__global__ __launch_bounds__(512, 1) void gather_kernel(
    const int* __restrict__ hist_tokens, const int* __restrict__ seg,
    const unsigned short* __restrict__ embb, unsigned short* __restrict__ histb)
{
    __shared__ int tokoff[PCHUNK * LL];
    const int b = blockIdx.x, tid = threadIdx.x;
    const int lo = lower_bound_i(seg, NP, b);
    const int hi = lower_bound_i(seg, NP, b + 1);
    const float inv = 1.0f / fmaxf((float)(hi - lo), 1.0f);

    int toff[8], doff[8];
    #pragma unroll
    for (int j = 0; j < 8; ++j) {
        int idx = tid + 512 * j;
        if (idx < 3750) { toff[j] = idx / 75; doff[j] = (idx % 75) * 4; }
        else            { toff[j] = 0;        doff[j] = 0; }
    }
    const bool has8 = (tid < 166);

    float4 acc[8];
    #pragma unroll
    for (int j = 0; j < 8; ++j) acc[j] = make_float4(0.f, 0.f, 0.f, 0.f);

    for (int p0 = lo; p0 < hi; p0 += PCHUNK) {
        const int pc = min(PCHUNK, hi - p0);
        __syncthreads();
        for (int j = tid; j < pc * LL; j += 512)
            tokoff[j] = hist_tokens[p0 * LL + j] * DD;
        __syncthreads();
        for (int pp = 0; pp < pc; ++pp) {
            const int* tr = tokoff + pp * LL;
            #pragma unroll
            for (int j = 0; j < 7; ++j) {
                const ushort4 v = *(const ushort4*)(embb + tr[toff[j]] + doff[j]);
                acc[j].x += bf2f(v.x); acc[j].y += bf2f(v.y);
                acc[j].z += bf2f(v.z); acc[j].w += bf2f(v.w);
            }
            if (has8) {
                const ushort4 v = *(const ushort4*)(embb + tr[toff[7]] + doff[7]);
                acc[7].x += bf2f(v.x); acc[7].y += bf2f(v.y);
                acc[7].z += bf2f(v.z); acc[7].w += bf2f(v.w);
            }
        }
    }

    unsigned short* hb = histb + (size_t)b * TP * DP;
    #pragma unroll
    for (int j = 0; j < 8; ++j) {
        if (j < 7 || has8) {
            ushort4 o;
            o.x = f2bf(acc[j].x * inv); o.y = f2bf(acc[j].y * inv);
            o.z = f2bf(acc[j].z * inv); o.w = f2bf(acc[j].w * inv);
            *(ushort4*)(hb + toff[j] * DP + doff[j]) = o;
        }
    }
    for (int i = tid; i < 640 + 1000; i += 512) {
        int t, d;
        if (i < 640) { t = 50 + i / 320; d = i % 320; }
        else         { int j = i - 640; t = j / 20; d = 300 + j % 20; }
        hb[t * DP + d] = 0;
    }
}

// ---- conv: 4 users/block, 12 waves = 4 users x 3 n-groups {0-6,7-13,14-18}.
//      Each wave: all 3 m-tiles x its n-group -> acc[3][7] (84 AGPR), 3 waves/SIMD.
//      BARRIER-FREE main loop:
//        * ALL of A (4 users x 52 rows x 320 d, 133 KB) resident in LDS, staged
//          once up front (linear copy), row stride padded to 328 shorts so the
//          16-row fragment ds_read_b128 is bank-uniform.
//        * B frags loaded per-wave straight from global W5f into registers
//          (coalesced 1KB wave-loads; table is L2-resident; the 4 user-waves
//          per CU read identical frags -> L1 dedup). No sB, no ds_writes,
//          no per-step barriers -- waves free-run, SIMD-balanced by wave=g*4+u.
//      Compile-time tap-skip as before: s=3 only tiles>=6, s=4 only >=12. ----
__global__ __launch_bounds__(768, 3) void conv_kernel(
    const unsigned short* __restrict__ histb, const unsigned short* __restrict__ W5f,
    const float* __restrict__ bias_all,
    const float* __restrict__ hist_w, const float* __restrict__ hist_b,
    float* __restrict__ out)
{
    __shared__ __align__(16) unsigned short sA[UPB * 52 * LDA];  // 136,448 B
    __shared__ __align__(16) float fpool[UPB * NPADF];           //   5,120 B

    const int b = blockIdx.x, tid = threadIdx.x;
    const int wave = tid >> 6, lane = tid & 63;
    const int col = lane & 15, quad = lane >> 4;
    const int u = wave & 3, g = wave >> 2;      // user 0..3, n-group 0..2
    const int base = (g == 2) ? 14 : g * 7;     // first tile of group
    const int cnt  = (g == 2) ? 5  : 7;         // live tiles in group

    const unsigned short* hbase = histb + (size_t)(b * UPB) * TP * DP;

    // ---- stage ALL of A: 208 rows x 320 shorts -> sA[row][LDA] (once) ----
    for (int i = tid; i < 208 * 40; i += 768) {
        const int r = i / 40, o = (i % 40) * 8;
        *(v8s*)(sA + r * LDA + o) = *(const v8s*)(hbase + r * DP + o);
    }

    v4f acc[3][7];
    #pragma unroll
    for (int m = 0; m < 3; ++m)
        #pragma unroll
        for (int j = 0; j < 7; ++j)
            acc[m][j] = (v4f){0.f, 0.f, 0.f, 0.f};

    __syncthreads();    // A visible; sA is read-only from here on

    for (int kt = 0; kt < 10; ++kt) {
        #pragma unroll
        for (int s = 0; s < 5; ++s) {
            const int step = kt * 5 + s;
            const int lo   = (s == 3) ? 6 : (s == 4) ? 12 : 0;   // live tiles [lo,19)
            const unsigned short* gb = W5f + (size_t)step * 10240;

            // -- B frags straight from global (coalesced; L1/L2-hot) --
            v8s bf[7];
            #pragma unroll
            for (int j = 0; j < 7; ++j) {
                const int t = base + j;
                if (j < cnt && t >= lo)
                    bf[j] = *(const v8s*)(gb + t * 512 + lane * 8);
            }
            // -- A frags from LDS --
            const unsigned short* Arow = sA + (u * 52 + col + s) * LDA + kt * 32 + quad * 8;
            const v8s am0 = *(const v8s*)(Arow);
            const v8s am1 = *(const v8s*)(Arow + 16 * LDA);
            const v8s am2 = *(const v8s*)(Arow + 32 * LDA);
            #pragma unroll
            for (int j = 0; j < 7; ++j) {
                const int t = base + j;
                if (j < cnt && t >= lo) {
                    acc[0][j] = __builtin_amdgcn_mfma_f32_16x16x32_bf16(am0, bf[j], acc[0][j], 0, 0, 0);
                    acc[1][j] = __builtin_amdgcn_mfma_f32_16x16x32_bf16(am1, bf[j], acc[1][j], 0, 0, 0);
                    acc[2][j] = __builtin_amdgcn_mfma_f32_16x16x32_bf16(am2, bf[j], acc[2][j], 0, 0, 0);
                }
            }
        }
    }

    // maxpool + bias + relu -> fpool (wave-local: each wave owns all m for its tiles)
    #pragma unroll
    for (int j = 0; j < 7; ++j) {
        if (j < cnt) {
            const int nf = (base + j) * 16 + col;
            const int Tout = 48 - nf / 100;        // 48/47/46 per class
            float mx = -1e30f;
            #pragma unroll
            for (int m = 0; m < 3; ++m)
                #pragma unroll
                for (int r = 0; r < 4; ++r) {
                    const int t = m * 16 + quad * 4 + r;
                    if (t < Tout) mx = fmaxf(mx, acc[m][j][r]);
                }
            mx = fmaxf(mx, __shfl_xor(mx, 16, 64));
            mx = fmaxf(mx, __shfl_xor(mx, 32, 64));
            if (quad == 0 && nf < NTOT)
                fpool[u * NPADF + nf] = fmaxf(0.f, mx + bias_all[nf]);
        }
    }
    __syncthreads();

    // rec = fpool @ hist_w.T + hist_b
    if (tid < UPB * 64) {
        const int uu = tid >> 6, o = tid & 63;
        const float4* fw = (const float4*)(hist_w + o * NTOT);
        const float4* fp = (const float4*)(fpool + uu * NPADF);
        float sum = 0.f;
        #pragma unroll
        for (int q = 0; q < NTOT / 4; ++q) {
            float4 aa = fp[q], ww = fw[q];
            sum += aa.x * ww.x + aa.y * ww.y + aa.z * ww.z + aa.w * ww.w;
        }
        out[(b * UPB + uu) * 64 + o] = sum + hist_b[o];
    }
}

// ---- fc via MFMA: h = relu(x[root] @ w1b.T + b1) ; out += h @ w2.T + b2 ----
__global__ __launch_bounds__(256, 1) void fc_mfma(
    const float* __restrict__ x, const int* __restrict__ rootindex,
    const unsigned short* __restrict__ w1b, const float* __restrict__ b1,
    const float* __restrict__ w2, const float* __restrict__ b2,
    float* __restrict__ out)
{
    __shared__ __align__(16) unsigned short sA[FCM * 72];   // 16 rows x 64k (pad 72)
    __shared__ __align__(16) float hl[FCM * 132];           // h tile, stride 132
    __shared__ __align__(16) float w2l[64 * 129];           // w2 staged, stride 129
    __shared__ int roots[FCM];

    const int b = blockIdx.x, tid = threadIdx.x;
    if (tid < FCM) roots[tid] = rootindex[b * FCM + tid];
    for (int i = tid; i < 64 * HID2; i += 256)
        w2l[(i >> 7) * 129 + (i & 127)] = w2[i];
    __syncthreads();

    const int wave = tid >> 6, lane = tid & 63;
    const int col = lane & 15, quad = lane >> 4;

    v4f acc[2];
    acc[0] = (v4f){0.f, 0.f, 0.f, 0.f};
    acc[1] = (v4f){0.f, 0.f, 0.f, 0.f};

    const int r_st = tid >> 4, q_st = tid & 15;

    for (int kt = 0; kt < 12; ++kt) {
        __syncthreads();
        float4 v = *(const float4*)(x + (size_t)roots[r_st] * INFEAT + kt * 64 + q_st * 4);
        ushort4 o; o.x = f2bf(v.x); o.y = f2bf(v.y); o.z = f2bf(v.z); o.w = f2bf(v.w);
        *(ushort4*)(sA + r_st * 72 + q_st * 4) = o;
        __syncthreads();
        #pragma unroll
        for (int kc = 0; kc < 2; ++kc) {
            const v8s a = *(const v8s*)(sA + col * 72 + kc * 32 + quad * 8);
            #pragma unroll
            for (int n = 0; n < 2; ++n) {
                const int nf = (wave * 2 + n) * 16 + col;
                const v8s bfr = *(const v8s*)(w1b + (size_t)nf * INFEAT + kt * 64 + kc * 32 + quad * 8);
                acc[n] = __builtin_amdgcn_mfma_f32_16x16x32_bf16(a, bfr, acc[n], 0, 0, 0);
            }
        }
    }

    #pragma unroll
    for (int nt = 0; nt < 2; ++nt) {
        const int n = (wave * 2 + nt) * 16 + col;
        const float bv = b1[n];
        #pragma unroll
        for (int r = 0; r < 4; ++r)
            hl[(quad * 4 + r) * 132 + n] = fmaxf(acc[nt][r] + bv, 0.f);
    }
    __syncthreads();

    {
        const int o = tid & 63, ug = tid >> 6;
        const float b2v = b2[o];
        const float* wrow = w2l + o * 129;
        #pragma unroll
        for (int i = 0; i < 4; ++i) {
            const int u = ug * 4 + i;
            const float* hrow = hl + u * 132;
            float s = 0.f;
            #pragma unroll 16
            for (int k = 0; k < HID2; ++k) s += hrow[k] * wrow[k];
            out[(b * FCM + u) * 64 + o] += s + b2v;
        }
    }
}

extern "C" void kernel_launch(void* const* d_in, const int* in_sizes, int n_in,
                              void* d_out, int out_size, void* d_ws, size_t ws_size,
                              hipStream_t stream) {
    const float* x        = (const float*)d_in[0];
    const int*   rootidx  = (const int*)d_in[1];
    const int*   hist_tok = (const int*)d_in[2];
    const int*   seg      = (const int*)d_in[3];
    const float* emb      = (const float*)d_in[4];
    const float* w3       = (const float*)d_in[5];
    const float* cb3      = (const float*)d_in[6];
    const float* w4       = (const float*)d_in[7];
    const float* cb4      = (const float*)d_in[8];
    const float* w5       = (const float*)d_in[9];
    const float* cb5      = (const float*)d_in[10];
    const float* hist_w   = (const float*)d_in[11];
    const float* hist_b   = (const float*)d_in[12];
    const float* fw1      = (const float*)d_in[13];
    const float* fb1      = (const float*)d_in[14];
    const float* fw2      = (const float*)d_in[15];
    const float* fb2      = (const float*)d_in[16];
    float* out = (float*)d_out;

    // workspace layout (bytes)
    char* ws = (char*)d_ws;
    unsigned short* emb_bf  = (unsigned short*)(ws);                    // 30,000,000 B
    unsigned short* hist_bf = (unsigned short*)(ws + 30000000);         // 68,157,440 B
    unsigned short* W5f     = (unsigned short*)(ws + 98157440);         //  1,024,000 B
    float*          bias_all= (float*)(ws + 99181440);                  //      1,280 B
    unsigned short* w1b     = (unsigned short*)(ws + 99182720);         //    196,608 B

    emb_cvt<<<(50000 * DD / 4 + 255) / 256, 256, 0, stream>>>(emb, emb_bf, 50000 * DD / 4);
    emb_cvt<<<(HID2 * INFEAT / 4 + 255) / 256, 256, 0, stream>>>(fw1, w1b, HID2 * INFEAT / 4);
    prep_w<<<(10 * 5 * 20 * 512 + 255) / 256, 256, 0, stream>>>(w3, w4, w5, cb3, cb4, cb5, W5f, bias_all);
    gather_kernel<<<NB, 512, 0, stream>>>(hist_tok, seg, emb_bf, hist_bf);
    conv_kernel<<<NB / UPB, 768, 0, stream>>>(hist_bf, W5f, bias_all, hist_w, hist_b, out);
    fc_mfma<<<NB / FCM, 256, 0, stream>>>(x, rootidx, w1b, fb1, fw2, fb2, out);
}

// Round 6
// 337.130 us; speedup vs baseline: 1.0960x; 1.0322x over previous
//
#include <hip/hip_runtime.h>

// Problem constants
#define NB    2048     // users / segments
#define NP    16384    // posts
#define LL    50       // tokens per post
#define DD    300      // embedding dim
#define DP    320      // d padded to multiple of 32 (MFMA K tiles)
#define TP    52       // t rows incl. zero pad (48 outputs + 4 shift overhang)
#define NTOT  300      // total filters (100 per conv)
#define NPADF 320      // filters padded to 20 N-tiles of 16
#define INFEAT 768
#define HID2  128
#define UPB   4        // users per conv block
#define FCM   16       // users per fc block

typedef short v8s __attribute__((ext_vector_type(8)));
typedef float v4f __attribute__((ext_vector_type(4)));

__device__ __forceinline__ unsigned short f2bf(float f) {
    union { float f; unsigned u; } v; v.f = f;
    return (unsigned short)((v.u + 0x7FFF + ((v.u >> 16) & 1)) >> 16);  // RNE
}
__device__ __forceinline__ float bf2f(unsigned short u) {
    union { unsigned u; float f; } v; v.u = ((unsigned)u) << 16; return v.f;
}
__device__ __forceinline__ int lower_bound_i(const int* __restrict__ a, int n, int v) {
    int lo = 0, hi = n;
    while (lo < hi) { int mid = (lo + hi) >> 1; if (a[mid] < v) lo = mid + 1; else hi = mid; }
    return lo;
}

// async global->LDS 16B copy: LDS dest = (uniform base) + lane*16 (HW-implicit),
// global src is per-lane. Pass src WITH lane offset, dst WITHOUT.
__device__ __forceinline__ void async_copy16(const void* g, void* l) {
    __builtin_amdgcn_global_load_lds(
        (const __attribute__((address_space(1))) unsigned int*)g,
        (__attribute__((address_space(3))) unsigned int*)l, 16, 0, 0);
}

// ---- generic fp32 -> bf16 (used for emb table and fc_w1) ----
__global__ void emb_cvt(const float* __restrict__ in, unsigned short* __restrict__ out, int n4) {
    int i = blockIdx.x * blockDim.x + threadIdx.x;
    if (i >= n4) return;
    float4 v = ((const float4*)in)[i];
    ushort4 o; o.x = f2bf(v.x); o.y = f2bf(v.y); o.z = f2bf(v.z); o.w = f2bf(v.w);
    ((ushort4*)out)[i] = o;
}

// ---- conv weights -> bf16 fragment-order W5f[step=kt*5+s][nt][lane][8] + bias_all ----
__global__ void prep_w(const float* __restrict__ w3, const float* __restrict__ w4,
                       const float* __restrict__ w5,
                       const float* __restrict__ b3, const float* __restrict__ b4,
                       const float* __restrict__ b5,
                       unsigned short* __restrict__ W5f, float* __restrict__ bias_all) {
    int idx = blockIdx.x * blockDim.x + threadIdx.x;
    if (idx < NPADF) {
        float bv = 0.f;
        if (idx < 100) bv = b3[idx];
        else if (idx < 200) bv = b4[idx - 100];
        else if (idx < 300) bv = b5[idx - 200];
        bias_all[idx] = bv;
    }
    if (idx >= 10 * 5 * 20 * 512) return;
    int j    = idx & 7;
    int lane = (idx >> 3) & 63;
    int rest = idx >> 9;            // kt*100 + s*20 + nt
    int nt = rest % 20;
    int s  = (rest / 20) % 5;
    int kt = rest / 100;
    int col = lane & 15, quad = lane >> 4;
    int nf = nt * 16 + col;
    int d  = kt * 32 + quad * 8 + j;
    float v = 0.f;
    if (nf < NTOT && d < DD) {
        int cls = nf / 100, f = nf % 100, K = cls + 3;
        if (s < K) {
            const float* w = (cls == 0) ? w3 : (cls == 1) ? w4 : w5;
            v = w[(f * DD + d) * K + s];
        }
    }
    W5f[idx] = f2bf(v);
}

// ---- ragged segment-mean -> bf16 hist[b][52][320], vectorized ushort4 gather ----
#define PCHUNK 32
__global__ __launch_bounds__(512, 1) void gather_kernel(
    const int* __restrict__ hist_tokens, const int* __restrict__ seg,
    const unsigned short* __restrict__ embb, unsigned short* __restrict__ histb)
{
    __shared__ int tokoff[PCHUNK * LL];
    const int b = blockIdx.x, tid = threadIdx.x;
    const int lo = lower_bound_i(seg, NP, b);
    const int hi = lower_bound_i(seg, NP, b + 1);
    const float inv = 1.0f / fmaxf((float)(hi - lo), 1.0f);

    int toff[8], doff[8];
    #pragma unroll
    for (int j = 0; j < 8; ++j) {
        int idx = tid + 512 * j;
        if (idx < 3750) { toff[j] = idx / 75; doff[j] = (idx % 75) * 4; }
        else            { toff[j] = 0;        doff[j] = 0; }
    }
    const bool has8 = (tid < 166);

    float4 acc[8];
    #pragma unroll
    for (int j = 0; j < 8; ++j) acc[j] = make_float4(0.f, 0.f, 0.f, 0.f);

    for (int p0 = lo; p0 < hi; p0 += PCHUNK) {
        const int pc = min(PCHUNK, hi - p0);
        __syncthreads();
        for (int j = tid; j < pc * LL; j += 512)
            tokoff[j] = hist_tokens[p0 * LL + j] * DD;
        __syncthreads();
        for (int pp = 0; pp < pc; ++pp) {
            const int* tr = tokoff + pp * LL;
            #pragma unroll
            for (int j = 0; j < 7; ++j) {
                const ushort4 v = *(const ushort4*)(embb + tr[toff[j]] + doff[j]);
                acc[j].x += bf2f(v.x); acc[j].y += bf2f(v.y);
                acc[j].z += bf2f(v.z); acc[j].w += bf2f(v.w);
            }
            if (has8) {
                const ushort4 v = *(const ushort4*)(embb + tr[toff[7]] + doff[7]);
                acc[7].x += bf2f(v.x); acc[7].y += bf2f(v.y);
                acc[7].z += bf2f(v.z); acc[7].w += bf2f(v.w);
            }
        }
    }

    unsigned short* hb = histb + (size_t)b * TP * DP;
    #pragma unroll
    for (int j = 0; j < 8; ++j) {
        if (j < 7 || has8) {
            ushort4 o;
            o.x = f2bf(acc[j].x * inv); o.y = f2bf(acc[j].y * inv);
            o.z = f2bf(acc[j].z * inv); o.w = f2bf(acc[j].w * inv);
            *(ushort4*)(hb + toff[j] * DP + doff[j]) = o;
        }
    }
    for (int i = tid; i < 640 + 1000; i += 512) {
        int t, d;
        if (i < 640) { t = 50 + i / 320; d = i % 320; }
        else         { int j = i - 640; t = j / 20; d = 300 + j % 20; }
        hb[t * DP + d] = 0;
    }
}

// ---- conv: 4 users/block, 12 waves = 4 users x 3 n-groups {0-6,7-13,14-18}.
//      Each wave: all 3 m-tiles x its n-group -> acc[3][7] (84 AGPR), 3 waves/SIMD.
//      PER-KT staging, 2 barriers per kt (20 total):
//        * B: all 5 steps' LIVE tiles (19+19+19+13+7 = 77 x 1KB) DMA'd via
//          global_load_lds into sBk once per kt. Compute phase reads B from
//          LDS -> the 50-step main loop has ZERO VMEM (no L2 latency, no
//          vmcnt/barrier entanglement). L2 B-traffic drops 4x (77KB/kt vs
//          4 user-waves x 77KB re-reading from L1/L2).
//        * A: per-kt 32-short slices, reg-staged + ds_write into stride-40
//          layout (conflict-free, r2-proven; DMA can't target padded strides).
//      Race-free: all LDS writes (DMA + A ds_write) live in [bar1,bar2];
//      all reads in [bar2, next bar1]. vmcnt(0) drain at bar2 completes the
//      per-wave DMA handshake. Tap-skip: s=3 only tiles>=6, s=4 only >=12. ----
__global__ __launch_bounds__(768, 3) void conv_kernel(
    const unsigned short* __restrict__ histb, const unsigned short* __restrict__ W5f,
    const float* __restrict__ bias_all,
    const float* __restrict__ hist_w, const float* __restrict__ hist_b,
    float* __restrict__ out)
{
    __shared__ __align__(16) unsigned short sA[UPB * 52 * 40];   // 16,640 B
    __shared__ __align__(16) unsigned short sBk[77 * 512];       // 78,848 B
    __shared__ __align__(16) float fpool[UPB * NPADF];           //  5,120 B

    const int b = blockIdx.x, tid = threadIdx.x;
    const int wave = tid >> 6, lane = tid & 63;
    const int col = lane & 15, quad = lane >> 4;
    const int u = wave & 3, g = wave >> 2;      // user 0..3, n-group 0..2
    const int base = (g == 2) ? 14 : g * 7;     // first tile of group
    const int cnt  = (g == 2) ? 5  : 7;         // live tiles in group

    const unsigned short* hbase = histb + (size_t)(b * UPB) * TP * DP;

    // A staging chunk decode (832 chunks: 4 users x 52 rows x 4 ch of 8 shorts)
    const int c0 = tid;
    const int a0_uu = c0 / 208, a0_r = c0 % 208;
    const int a0_row = a0_r >> 2, a0_ch = a0_r & 3;
    const int c1 = tid + 768;
    const int a1_uu = c1 / 208, a1_r = c1 % 208;
    const int a1_row = a1_r >> 2, a1_ch = a1_r & 3;
    const bool hasA1 = (tid < 64);              // 832 - 768

    v4f acc[3][7];
    #pragma unroll
    for (int m = 0; m < 3; ++m)
        #pragma unroll
        for (int j = 0; j < 7; ++j)
            acc[m][j] = (v4f){0.f, 0.f, 0.f, 0.f};

    v8s a0v, a1v;

    // ---- B DMA for one kt: 77 live 1KB tile-chunks, cooperatively by 12 waves ----
    // LDS layout: block index = cumbase[s] + (t - lo_s), t live in [lo_s, 19).
    #define STAGE_B(KT)                                                              \
    {                                                                                \
        const unsigned short* wkt = W5f + (size_t)(KT) * 51200;                      \
        _Pragma("unroll")                                                            \
        for (int s5 = 0; s5 < 5; ++s5) {                                             \
            const int Ls  = (s5 < 3) ? 19 : (s5 == 3 ? 13 : 7);                      \
            const int los = (s5 < 3) ? 0  : (s5 == 3 ? 6  : 12);                     \
            const int cbs = (s5 < 3) ? 19 * s5 : (s5 == 3 ? 57 : 70);                \
            const unsigned short* srcs = wkt + s5 * 10240 + los * 512 + lane * 8;    \
            unsigned short* dsts = sBk + cbs * 512;                                  \
            if (wave < Ls)                                                           \
                async_copy16(srcs + wave * 512, dsts + wave * 512);                  \
            if (wave + 12 < Ls)                                                      \
                async_copy16(srcs + (wave + 12) * 512, dsts + (wave + 12) * 512);    \
        }                                                                            \
    }

    // ---- prologue: stage kt=0 (A regs -> ds_write; B DMA), one barrier ----
    a0v = *(const v8s*)(hbase + (size_t)a0_uu * TP * DP + a0_row * DP + a0_ch * 8);
    if (hasA1)
        a1v = *(const v8s*)(hbase + (size_t)a1_uu * TP * DP + a1_row * DP + a1_ch * 8);
    STAGE_B(0);
    *(v8s*)(sA + (a0_uu * 52 + a0_row) * 40 + a0_ch * 8) = a0v;
    if (hasA1) *(v8s*)(sA + (a1_uu * 52 + a1_row) * 40 + a1_ch * 8) = a1v;
    __syncthreads();    // drains DMA + A writes; everything visible

    for (int kt = 0; kt < 10; ++kt) {
        // issue next kt's A reg-loads early (pure VGPR, overlaps compute)
        if (kt < 9) {
            const int ko = (kt + 1) * 32;
            a0v = *(const v8s*)(hbase + (size_t)a0_uu * TP * DP + a0_row * DP + ko + a0_ch * 8);
            if (hasA1)
                a1v = *(const v8s*)(hbase + (size_t)a1_uu * TP * DP + a1_row * DP + ko + a1_ch * 8);
        }

        // ---- compute: 5 steps, pure LDS + MFMA ----
        #pragma unroll
        for (int s = 0; s < 5; ++s) {
            const int lo  = (s == 3) ? 6 : (s == 4) ? 12 : 0;
            const int cbs = (s < 3) ? 19 * s : (s == 3 ? 57 : 70);

            const unsigned short* Arow = sA + (u * 52 + col + s) * 40 + quad * 8;
            const v8s am0 = *(const v8s*)(Arow);
            const v8s am1 = *(const v8s*)(Arow + 640);    // +16 rows * 40
            const v8s am2 = *(const v8s*)(Arow + 1280);   // +32 rows * 40
            #pragma unroll
            for (int j = 0; j < 7; ++j) {
                const int t = base + j;
                if (j < cnt && t >= lo) {
                    const int blk = cbs + (t - lo);
                    const v8s bf = *(const v8s*)(sBk + blk * 512 + lane * 8);
                    acc[0][j] = __builtin_amdgcn_mfma_f32_16x16x32_bf16(am0, bf, acc[0][j], 0, 0, 0);
                    acc[1][j] = __builtin_amdgcn_mfma_f32_16x16x32_bf16(am1, bf, acc[1][j], 0, 0, 0);
                    acc[2][j] = __builtin_amdgcn_mfma_f32_16x16x32_bf16(am2, bf, acc[2][j], 0, 0, 0);
                }
            }
        }

        // ---- stage kt+1 in a clean 2-barrier window ----
        if (kt < 9) {
            __syncthreads();               // bar1: all reads of sA/sBk done
            STAGE_B(kt + 1);
            *(v8s*)(sA + (a0_uu * 52 + a0_row) * 40 + a0_ch * 8) = a0v;
            if (hasA1) *(v8s*)(sA + (a1_uu * 52 + a1_row) * 40 + a1_ch * 8) = a1v;
            __syncthreads();               // bar2: vmcnt(0) drain -> staged visible
        }
    }
    #undef STAGE_B

    // maxpool + bias + relu -> fpool (wave-local: each wave owns all m for its tiles)
    #pragma unroll
    for (int j = 0; j < 7; ++j) {
        if (j < cnt) {
            const int nf = (base + j) * 16 + col;
            const int Tout = 48 - nf / 100;        // 48/47/46 per class
            float mx = -1e30f;
            #pragma unroll
            for (int m = 0; m < 3; ++m)
                #pragma unroll
                for (int r = 0; r < 4; ++r) {
                    const int t = m * 16 + quad * 4 + r;
                    if (t < Tout) mx = fmaxf(mx, acc[m][j][r]);
                }
            mx = fmaxf(mx, __shfl_xor(mx, 16, 64));
            mx = fmaxf(mx, __shfl_xor(mx, 32, 64));
            if (quad == 0 && nf < NTOT)
                fpool[u * NPADF + nf] = fmaxf(0.f, mx + bias_all[nf]);
        }
    }
    __syncthreads();

    // rec = fpool @ hist_w.T + hist_b
    if (tid < UPB * 64) {
        const int uu = tid >> 6, o = tid & 63;
        const float4* fw = (const float4*)(hist_w + o * NTOT);
        const float4* fp = (const float4*)(fpool + uu * NPADF);
        float sum = 0.f;
        #pragma unroll
        for (int q = 0; q < NTOT / 4; ++q) {
            float4 aa = fp[q], ww = fw[q];
            sum += aa.x * ww.x + aa.y * ww.y + aa.z * ww.z + aa.w * ww.w;
        }
        out[(b * UPB + uu) * 64 + o] = sum + hist_b[o];
    }
}

// ---- fc via MFMA: h = relu(x[root] @ w1b.T + b1) ; out += h @ w2.T + b2 ----
__global__ __launch_bounds__(256, 1) void fc_mfma(
    const float* __restrict__ x, const int* __restrict__ rootindex,
    const unsigned short* __restrict__ w1b, const float* __restrict__ b1,
    const float* __restrict__ w2, const float* __restrict__ b2,
    float* __restrict__ out)
{
    __shared__ __align__(16) unsigned short sA[FCM * 72];   // 16 rows x 64k (pad 72)
    __shared__ __align__(16) float hl[FCM * 132];           // h tile, stride 132
    __shared__ __align__(16) float w2l[64 * 129];           // w2 staged, stride 129
    __shared__ int roots[FCM];

    const int b = blockIdx.x, tid = threadIdx.x;
    if (tid < FCM) roots[tid] = rootindex[b * FCM + tid];
    for (int i = tid; i < 64 * HID2; i += 256)
        w2l[(i >> 7) * 129 + (i & 127)] = w2[i];
    __syncthreads();

    const int wave = tid >> 6, lane = tid & 63;
    const int col = lane & 15, quad = lane >> 4;

    v4f acc[2];
    acc[0] = (v4f){0.f, 0.f, 0.f, 0.f};
    acc[1] = (v4f){0.f, 0.f, 0.f, 0.f};

    const int r_st = tid >> 4, q_st = tid & 15;

    for (int kt = 0; kt < 12; ++kt) {
        __syncthreads();
        float4 v = *(const float4*)(x + (size_t)roots[r_st] * INFEAT + kt * 64 + q_st * 4);
        ushort4 o; o.x = f2bf(v.x); o.y = f2bf(v.y); o.z = f2bf(v.z); o.w = f2bf(v.w);
        *(ushort4*)(sA + r_st * 72 + q_st * 4) = o;
        __syncthreads();
        #pragma unroll
        for (int kc = 0; kc < 2; ++kc) {
            const v8s a = *(const v8s*)(sA + col * 72 + kc * 32 + quad * 8);
            #pragma unroll
            for (int n = 0; n < 2; ++n) {
                const int nf = (wave * 2 + n) * 16 + col;
                const v8s bfr = *(const v8s*)(w1b + (size_t)nf * INFEAT + kt * 64 + kc * 32 + quad * 8);
                acc[n] = __builtin_amdgcn_mfma_f32_16x16x32_bf16(a, bfr, acc[n], 0, 0, 0);
            }
        }
    }

    #pragma unroll
    for (int nt = 0; nt < 2; ++nt) {
        const int n = (wave * 2 + nt) * 16 + col;
        const float bv = b1[n];
        #pragma unroll
        for (int r = 0; r < 4; ++r)
            hl[(quad * 4 + r) * 132 + n] = fmaxf(acc[nt][r] + bv, 0.f);
    }
    __syncthreads();

    {
        const int o = tid & 63, ug = tid >> 6;
        const float b2v = b2[o];
        const float* wrow = w2l + o * 129;
        #pragma unroll
        for (int i = 0; i < 4; ++i) {
            const int u = ug * 4 + i;
            const float* hrow = hl + u * 132;
            float s = 0.f;
            #pragma unroll 16
            for (int k = 0; k < HID2; ++k) s += hrow[k] * wrow[k];
            out[(b * FCM + u) * 64 + o] += s + b2v;
        }
    }
}

extern "C" void kernel_launch(void* const* d_in, const int* in_sizes, int n_in,
                              void* d_out, int out_size, void* d_ws, size_t ws_size,
                              hipStream_t stream) {
    const float* x        = (const float*)d_in[0];
    const int*   rootidx  = (const int*)d_in[1];
    const int*   hist_tok = (const int*)d_in[2];
    const int*   seg      = (const int*)d_in[3];
    const float* emb      = (const float*)d_in[4];
    const float* w3       = (const float*)d_in[5];
    const float* cb3      = (const float*)d_in[6];
    const float* w4       = (const float*)d_in[7];
    const float* cb4      = (const float*)d_in[8];
    const float* w5       = (const float*)d_in[9];
    const float* cb5      = (const float*)d_in[10];
    const float* hist_w   = (const float*)d_in[11];
    const float* hist_b   = (const float*)d_in[12];
    const float* fw1      = (const float*)d_in[13];
    const float* fb1      = (const float*)d_in[14];
    const float* fw2      = (const float*)d_in[15];
    const float* fb2      = (const float*)d_in[16];
    float* out = (float*)d_out;

    // workspace layout (bytes)
    char* ws = (char*)d_ws;
    unsigned short* emb_bf  = (unsigned short*)(ws);                    // 30,000,000 B
    unsigned short* hist_bf = (unsigned short*)(ws + 30000000);         // 68,157,440 B
    unsigned short* W5f     = (unsigned short*)(ws + 98157440);         //  1,024,000 B
    float*          bias_all= (float*)(ws + 99181440);                  //      1,280 B
    unsigned short* w1b     = (unsigned short*)(ws + 99182720);         //    196,608 B

    emb_cvt<<<(50000 * DD / 4 + 255) / 256, 256, 0, stream>>>(emb, emb_bf, 50000 * DD / 4);
    emb_cvt<<<(HID2 * INFEAT / 4 + 255) / 256, 256, 0, stream>>>(fw1, w1b, HID2 * INFEAT / 4);
    prep_w<<<(10 * 5 * 20 * 512 + 255) / 256, 256, 0, stream>>>(w3, w4, w5, cb3, cb4, cb5, W5f, bias_all);
    gather_kernel<<<NB, 512, 0, stream>>>(hist_tok, seg, emb_bf, hist_bf);
    conv_kernel<<<NB / UPB, 768, 0, stream>>>(hist_bf, W5f, bias_all, hist_w, hist_b, out);
    fc_mfma<<<NB / FCM, 256, 0, stream>>>(x, rootidx, w1b, fb1, fw2, fb2, out);
}

// Round 7
// 335.983 us; speedup vs baseline: 1.0997x; 1.0034x over previous
//
#include <hip/hip_runtime.h>

// Problem constants
#define NB    2048     // users / segments
#define NP    16384    // posts
#define LL    50       // tokens per post
#define DD    300      // embedding dim
#define DP    320      // d padded to multiple of 32 (MFMA K tiles)
#define TP    52       // t rows incl. zero pad (48 outputs + 4 shift overhang)
#define NTOT  300      // total filters (100 per conv)
#define NPADF 320      // filters padded to 20 N-tiles of 16
#define INFEAT 768
#define HID2  128
#define UPB   4        // users per conv block
#define FCM   16       // users per fc block

typedef short v8s __attribute__((ext_vector_type(8)));
typedef float v4f __attribute__((ext_vector_type(4)));
typedef unsigned short v4u __attribute__((ext_vector_type(4)));

__device__ __forceinline__ unsigned short f2bf(float f) {
    union { float f; unsigned u; } v; v.f = f;
    return (unsigned short)((v.u + 0x7FFF + ((v.u >> 16) & 1)) >> 16);  // RNE
}
__device__ __forceinline__ float bf2f(unsigned short u) {
    union { unsigned u; float f; } v; v.u = ((unsigned)u) << 16; return v.f;
}
__device__ __forceinline__ int lower_bound_i(const int* __restrict__ a, int n, int v) {
    int lo = 0, hi = n;
    while (lo < hi) { int mid = (lo + hi) >> 1; if (a[mid] < v) lo = mid + 1; else hi = mid; }
    return lo;
}

// async global->LDS 16B copy: LDS dest = (uniform base) + lane*16 (HW-implicit),
// global src is per-lane. Pass src WITH lane offset, dst WITHOUT.
__device__ __forceinline__ void async_copy16(const void* g, void* l) {
    __builtin_amdgcn_global_load_lds(
        (const __attribute__((address_space(1))) unsigned int*)g,
        (__attribute__((address_space(3))) unsigned int*)l, 16, 0, 0);
}

// ---- fp32 -> bf16 for emb table (grid-stride) ----
__global__ void emb_cvt(const float* __restrict__ in, unsigned short* __restrict__ out, int n4) {
    for (int i = blockIdx.x * blockDim.x + threadIdx.x; i < n4; i += gridDim.x * blockDim.x) {
        float4 v = ((const float4*)in)[i];
        ushort4 o; o.x = f2bf(v.x); o.y = f2bf(v.y); o.z = f2bf(v.z); o.w = f2bf(v.w);
        ((ushort4*)out)[i] = o;
    }
}

// ---- conv weights -> bf16 fragment-order W5f[step=kt*5+s][nt][lane][8] + bias_all
//      + fc_w1 fp32->bf16 (folded in to drop one launch) ----
__global__ void prep_w(const float* __restrict__ w3, const float* __restrict__ w4,
                       const float* __restrict__ w5,
                       const float* __restrict__ b3, const float* __restrict__ b4,
                       const float* __restrict__ b5,
                       unsigned short* __restrict__ W5f, float* __restrict__ bias_all,
                       const float* __restrict__ fw1, unsigned short* __restrict__ w1b) {
    int idx = blockIdx.x * blockDim.x + threadIdx.x;
    if (idx < HID2 * INFEAT / 4) {          // 24576 float4s of fc_w1
        float4 v = ((const float4*)fw1)[idx];
        ushort4 o; o.x = f2bf(v.x); o.y = f2bf(v.y); o.z = f2bf(v.z); o.w = f2bf(v.w);
        ((ushort4*)w1b)[idx] = o;
    }
    if (idx < NPADF) {
        float bv = 0.f;
        if (idx < 100) bv = b3[idx];
        else if (idx < 200) bv = b4[idx - 100];
        else if (idx < 300) bv = b5[idx - 200];
        bias_all[idx] = bv;
    }
    if (idx >= 10 * 5 * 20 * 512) return;
    int j    = idx & 7;
    int lane = (idx >> 3) & 63;
    int rest = idx >> 9;            // kt*100 + s*20 + nt
    int nt = rest % 20;
    int s  = (rest / 20) % 5;
    int kt = rest / 100;
    int col = lane & 15, quad = lane >> 4;
    int nf = nt * 16 + col;
    int d  = kt * 32 + quad * 8 + j;
    float v = 0.f;
    if (nf < NTOT && d < DD) {
        int cls = nf / 100, f = nf % 100, K = cls + 3;
        if (s < K) {
            const float* w = (cls == 0) ? w3 : (cls == 1) ? w4 : w5;
            v = w[(f * DD + d) * K + s];
        }
    }
    W5f[idx] = f2bf(v);
}

// ---- ragged segment-mean -> bf16 hist[b][52][320].
//      2-post batched loads (16 outstanding/wave) + NONTEMPORAL hist stores
//      (don't let the 68MB write stream evict the 30MB emb table from L3). ----
#define PCHUNK 32
__global__ __launch_bounds__(512, 1) void gather_kernel(
    const int* __restrict__ hist_tokens, const int* __restrict__ seg,
    const unsigned short* __restrict__ embb, unsigned short* __restrict__ histb)
{
    __shared__ int tokoff[PCHUNK * LL];
    const int b = blockIdx.x, tid = threadIdx.x;
    const int lo = lower_bound_i(seg, NP, b);
    const int hi = lower_bound_i(seg, NP, b + 1);
    const float inv = 1.0f / fmaxf((float)(hi - lo), 1.0f);

    int toff[8], doff[8];
    #pragma unroll
    for (int j = 0; j < 8; ++j) {
        int idx = tid + 512 * j;
        if (idx < 3750) { toff[j] = idx / 75; doff[j] = (idx % 75) * 4; }
        else            { toff[j] = 0;        doff[j] = 0; }
    }
    const bool has8 = (tid < 166);

    float4 acc[8];
    #pragma unroll
    for (int j = 0; j < 8; ++j) acc[j] = make_float4(0.f, 0.f, 0.f, 0.f);

    for (int p0 = lo; p0 < hi; p0 += PCHUNK) {
        const int pc = min(PCHUNK, hi - p0);
        __syncthreads();
        for (int j = tid; j < pc * LL; j += 512)
            tokoff[j] = hist_tokens[p0 * LL + j] * DD;
        __syncthreads();
        int pp = 0;
        for (; pp + 1 < pc; pp += 2) {
            const int* trA = tokoff + pp * LL;
            const int* trB = trA + LL;
            ushort4 va[8], vb[8];
            #pragma unroll
            for (int j = 0; j < 7; ++j)
                va[j] = *(const ushort4*)(embb + trA[toff[j]] + doff[j]);
            if (has8) va[7] = *(const ushort4*)(embb + trA[toff[7]] + doff[7]);
            #pragma unroll
            for (int j = 0; j < 7; ++j)
                vb[j] = *(const ushort4*)(embb + trB[toff[j]] + doff[j]);
            if (has8) vb[7] = *(const ushort4*)(embb + trB[toff[7]] + doff[7]);
            #pragma unroll
            for (int j = 0; j < 8; ++j) {
                if (j < 7 || has8) {
                    acc[j].x += bf2f(va[j].x) + bf2f(vb[j].x);
                    acc[j].y += bf2f(va[j].y) + bf2f(vb[j].y);
                    acc[j].z += bf2f(va[j].z) + bf2f(vb[j].z);
                    acc[j].w += bf2f(va[j].w) + bf2f(vb[j].w);
                }
            }
        }
        if (pp < pc) {
            const int* tr = tokoff + pp * LL;
            ushort4 v[8];
            #pragma unroll
            for (int j = 0; j < 7; ++j)
                v[j] = *(const ushort4*)(embb + tr[toff[j]] + doff[j]);
            if (has8) v[7] = *(const ushort4*)(embb + tr[toff[7]] + doff[7]);
            #pragma unroll
            for (int j = 0; j < 8; ++j) {
                if (j < 7 || has8) {
                    acc[j].x += bf2f(v[j].x); acc[j].y += bf2f(v[j].y);
                    acc[j].z += bf2f(v[j].z); acc[j].w += bf2f(v[j].w);
                }
            }
        }
    }

    unsigned short* hb = histb + (size_t)b * TP * DP;
    #pragma unroll
    for (int j = 0; j < 8; ++j) {
        if (j < 7 || has8) {
            v4u o;
            o[0] = f2bf(acc[j].x * inv); o[1] = f2bf(acc[j].y * inv);
            o[2] = f2bf(acc[j].z * inv); o[3] = f2bf(acc[j].w * inv);
            __builtin_nontemporal_store(o, (v4u*)(hb + toff[j] * DP + doff[j]));
        }
    }
    for (int i = tid; i < 640 + 1000; i += 512) {
        int t, d;
        if (i < 640) { t = 50 + i / 320; d = i % 320; }
        else         { int j = i - 640; t = j / 20; d = 300 + j % 20; }
        __builtin_nontemporal_store((unsigned short)0, hb + t * DP + d);
    }
}

// ---- conv: 4 users/block, 12 waves = 4 users x 3 n-groups {0-6,7-13,14-18}.
//      Each wave: all 3 m-tiles x its n-group -> acc[3][7] (84 AGPR), 3 waves/SIMD.
//      PER-KT staging (r6-proven), 2 barriers per kt; compute phase pure LDS+MFMA.
//      setprio(1) around each step's MFMA batch (T5; waves drift within compute). ----
__global__ __launch_bounds__(768, 3) void conv_kernel(
    const unsigned short* __restrict__ histb, const unsigned short* __restrict__ W5f,
    const float* __restrict__ bias_all,
    const float* __restrict__ hist_w, const float* __restrict__ hist_b,
    float* __restrict__ out)
{
    __shared__ __align__(16) unsigned short sA[UPB * 52 * 40];   // 16,640 B
    __shared__ __align__(16) unsigned short sBk[77 * 512];       // 78,848 B
    __shared__ __align__(16) float fpool[UPB * NPADF];           //  5,120 B

    const int b = blockIdx.x, tid = threadIdx.x;
    const int wave = tid >> 6, lane = tid & 63;
    const int col = lane & 15, quad = lane >> 4;
    const int u = wave & 3, g = wave >> 2;      // user 0..3, n-group 0..2
    const int base = (g == 2) ? 14 : g * 7;     // first tile of group
    const int cnt  = (g == 2) ? 5  : 7;         // live tiles in group

    const unsigned short* hbase = histb + (size_t)(b * UPB) * TP * DP;

    // A staging chunk decode (832 chunks: 4 users x 52 rows x 4 ch of 8 shorts)
    const int c0 = tid;
    const int a0_uu = c0 / 208, a0_r = c0 % 208;
    const int a0_row = a0_r >> 2, a0_ch = a0_r & 3;
    const int c1 = tid + 768;
    const int a1_uu = c1 / 208, a1_r = c1 % 208;
    const int a1_row = a1_r >> 2, a1_ch = a1_r & 3;
    const bool hasA1 = (tid < 64);              // 832 - 768

    v4f acc[3][7];
    #pragma unroll
    for (int m = 0; m < 3; ++m)
        #pragma unroll
        for (int j = 0; j < 7; ++j)
            acc[m][j] = (v4f){0.f, 0.f, 0.f, 0.f};

    v8s a0v, a1v;

    // ---- B DMA for one kt: 77 live 1KB tile-chunks, cooperatively by 12 waves ----
    #define STAGE_B(KT)                                                              \
    {                                                                                \
        const unsigned short* wkt = W5f + (size_t)(KT) * 51200;                      \
        _Pragma("unroll")                                                            \
        for (int s5 = 0; s5 < 5; ++s5) {                                             \
            const int Ls  = (s5 < 3) ? 19 : (s5 == 3 ? 13 : 7);                      \
            const int los = (s5 < 3) ? 0  : (s5 == 3 ? 6  : 12);                     \
            const int cbs = (s5 < 3) ? 19 * s5 : (s5 == 3 ? 57 : 70);                \
            const unsigned short* srcs = wkt + s5 * 10240 + los * 512 + lane * 8;    \
            unsigned short* dsts = sBk + cbs * 512;                                  \
            if (wave < Ls)                                                           \
                async_copy16(srcs + wave * 512, dsts + wave * 512);                  \
            if (wave + 12 < Ls)                                                      \
                async_copy16(srcs + (wave + 12) * 512, dsts + (wave + 12) * 512);    \
        }                                                                            \
    }

    // ---- prologue: stage kt=0 (A regs -> ds_write; B DMA), one barrier ----
    a0v = *(const v8s*)(hbase + (size_t)a0_uu * TP * DP + a0_row * DP + a0_ch * 8);
    if (hasA1)
        a1v = *(const v8s*)(hbase + (size_t)a1_uu * TP * DP + a1_row * DP + a1_ch * 8);
    STAGE_B(0);
    *(v8s*)(sA + (a0_uu * 52 + a0_row) * 40 + a0_ch * 8) = a0v;
    if (hasA1) *(v8s*)(sA + (a1_uu * 52 + a1_row) * 40 + a1_ch * 8) = a1v;
    __syncthreads();    // drains DMA + A writes; everything visible

    for (int kt = 0; kt < 10; ++kt) {
        // issue next kt's A reg-loads early (pure VGPR, overlaps compute)
        if (kt < 9) {
            const int ko = (kt + 1) * 32;
            a0v = *(const v8s*)(hbase + (size_t)a0_uu * TP * DP + a0_row * DP + ko + a0_ch * 8);
            if (hasA1)
                a1v = *(const v8s*)(hbase + (size_t)a1_uu * TP * DP + a1_row * DP + ko + a1_ch * 8);
        }

        // ---- compute: 5 steps, pure LDS + MFMA ----
        #pragma unroll
        for (int s = 0; s < 5; ++s) {
            const int lo  = (s == 3) ? 6 : (s == 4) ? 12 : 0;
            const int cbs = (s < 3) ? 19 * s : (s == 3 ? 57 : 70);

            const unsigned short* Arow = sA + (u * 52 + col + s) * 40 + quad * 8;
            const v8s am0 = *(const v8s*)(Arow);
            const v8s am1 = *(const v8s*)(Arow + 640);    // +16 rows * 40
            const v8s am2 = *(const v8s*)(Arow + 1280);   // +32 rows * 40
            __builtin_amdgcn_s_setprio(1);
            #pragma unroll
            for (int j = 0; j < 7; ++j) {
                const int t = base + j;
                if (j < cnt && t >= lo) {
                    const int blk = cbs + (t - lo);
                    const v8s bf = *(const v8s*)(sBk + blk * 512 + lane * 8);
                    acc[0][j] = __builtin_amdgcn_mfma_f32_16x16x32_bf16(am0, bf, acc[0][j], 0, 0, 0);
                    acc[1][j] = __builtin_amdgcn_mfma_f32_16x16x32_bf16(am1, bf, acc[1][j], 0, 0, 0);
                    acc[2][j] = __builtin_amdgcn_mfma_f32_16x16x32_bf16(am2, bf, acc[2][j], 0, 0, 0);
                }
            }
            __builtin_amdgcn_s_setprio(0);
        }

        // ---- stage kt+1 in a clean 2-barrier window ----
        if (kt < 9) {
            __syncthreads();               // bar1: all reads of sA/sBk done
            STAGE_B(kt + 1);
            *(v8s*)(sA + (a0_uu * 52 + a0_row) * 40 + a0_ch * 8) = a0v;
            if (hasA1) *(v8s*)(sA + (a1_uu * 52 + a1_row) * 40 + a1_ch * 8) = a1v;
            __syncthreads();               // bar2: vmcnt(0) drain -> staged visible
        }
    }
    #undef STAGE_B

    // maxpool + bias + relu -> fpool (wave-local: each wave owns all m for its tiles)
    #pragma unroll
    for (int j = 0; j < 7; ++j) {
        if (j < cnt) {
            const int nf = (base + j) * 16 + col;
            const int Tout = 48 - nf / 100;        // 48/47/46 per class
            float mx = -1e30f;
            #pragma unroll
            for (int m = 0; m < 3; ++m)
                #pragma unroll
                for (int r = 0; r < 4; ++r) {
                    const int t = m * 16 + quad * 4 + r;
                    if (t < Tout) mx = fmaxf(mx, acc[m][j][r]);
                }
            mx = fmaxf(mx, __shfl_xor(mx, 16, 64));
            mx = fmaxf(mx, __shfl_xor(mx, 32, 64));
            if (quad == 0 && nf < NTOT)
                fpool[u * NPADF + nf] = fmaxf(0.f, mx + bias_all[nf]);
        }
    }
    __syncthreads();

    // rec = fpool @ hist_w.T + hist_b
    if (tid < UPB * 64) {
        const int uu = tid >> 6, o = tid & 63;
        const float4* fw = (const float4*)(hist_w + o * NTOT);
        const float4* fp = (const float4*)(fpool + uu * NPADF);
        float sum = 0.f;
        #pragma unroll
        for (int q = 0; q < NTOT / 4; ++q) {
            float4 aa = fp[q], ww = fw[q];
            sum += aa.x * ww.x + aa.y * ww.y + aa.z * ww.z + aa.w * ww.w;
        }
        out[(b * UPB + uu) * 64 + o] = sum + hist_b[o];
    }
}

// ---- fc via MFMA: h = relu(x[root] @ w1b.T + b1) ; out += h @ w2.T + b2 ----
__global__ __launch_bounds__(256, 1) void fc_mfma(
    const float* __restrict__ x, const int* __restrict__ rootindex,
    const unsigned short* __restrict__ w1b, const float* __restrict__ b1,
    const float* __restrict__ w2, const float* __restrict__ b2,
    float* __restrict__ out)
{
    __shared__ __align__(16) unsigned short sA[FCM * 72];   // 16 rows x 64k (pad 72)
    __shared__ __align__(16) float hl[FCM * 132];           // h tile, stride 132
    __shared__ __align__(16) float w2l[64 * 129];           // w2 staged, stride 129
    __shared__ int roots[FCM];

    const int b = blockIdx.x, tid = threadIdx.x;
    if (tid < FCM) roots[tid] = rootindex[b * FCM + tid];
    for (int i = tid; i < 64 * HID2; i += 256)
        w2l[(i >> 7) * 129 + (i & 127)] = w2[i];
    __syncthreads();

    const int wave = tid >> 6, lane = tid & 63;
    const int col = lane & 15, quad = lane >> 4;

    v4f acc[2];
    acc[0] = (v4f){0.f, 0.f, 0.f, 0.f};
    acc[1] = (v4f){0.f, 0.f, 0.f, 0.f};

    const int r_st = tid >> 4, q_st = tid & 15;

    for (int kt = 0; kt < 12; ++kt) {
        __syncthreads();
        float4 v = *(const float4*)(x + (size_t)roots[r_st] * INFEAT + kt * 64 + q_st * 4);
        ushort4 o; o.x = f2bf(v.x); o.y = f2bf(v.y); o.z = f2bf(v.z); o.w = f2bf(v.w);
        *(ushort4*)(sA + r_st * 72 + q_st * 4) = o;
        __syncthreads();
        #pragma unroll
        for (int kc = 0; kc < 2; ++kc) {
            const v8s a = *(const v8s*)(sA + col * 72 + kc * 32 + quad * 8);
            #pragma unroll
            for (int n = 0; n < 2; ++n) {
                const int nf = (wave * 2 + n) * 16 + col;
                const v8s bfr = *(const v8s*)(w1b + (size_t)nf * INFEAT + kt * 64 + kc * 32 + quad * 8);
                acc[n] = __builtin_amdgcn_mfma_f32_16x16x32_bf16(a, bfr, acc[n], 0, 0, 0);
            }
        }
    }

    #pragma unroll
    for (int nt = 0; nt < 2; ++nt) {
        const int n = (wave * 2 + nt) * 16 + col;
        const float bv = b1[n];
        #pragma unroll
        for (int r = 0; r < 4; ++r)
            hl[(quad * 4 + r) * 132 + n] = fmaxf(acc[nt][r] + bv, 0.f);
    }
    __syncthreads();

    {
        const int o = tid & 63, ug = tid >> 6;
        const float b2v = b2[o];
        const float* wrow = w2l + o * 129;
        #pragma unroll
        for (int i = 0; i < 4; ++i) {
            const int u = ug * 4 + i;
            const float* hrow = hl + u * 132;
            float s = 0.f;
            #pragma unroll 16
            for (int k = 0; k < HID2; ++k) s += hrow[k] * wrow[k];
            out[(b * FCM + u) * 64 + o] += s + b2v;
        }
    }
}

extern "C" void kernel_launch(void* const* d_in, const int* in_sizes, int n_in,
                              void* d_out, int out_size, void* d_ws, size_t ws_size,
                              hipStream_t stream) {
    const float* x        = (const float*)d_in[0];
    const int*   rootidx  = (const int*)d_in[1];
    const int*   hist_tok = (const int*)d_in[2];
    const int*   seg      = (const int*)d_in[3];
    const float* emb      = (const float*)d_in[4];
    const float* w3       = (const float*)d_in[5];
    const float* cb3      = (const float*)d_in[6];
    const float* w4       = (const float*)d_in[7];
    const float* cb4      = (const float*)d_in[8];
    const float* w5       = (const float*)d_in[9];
    const float* cb5      = (const float*)d_in[10];
    const float* hist_w   = (const float*)d_in[11];
    const float* hist_b   = (const float*)d_in[12];
    const float* fw1      = (const float*)d_in[13];
    const float* fb1      = (const float*)d_in[14];
    const float* fw2      = (const float*)d_in[15];
    const float* fb2      = (const float*)d_in[16];
    float* out = (float*)d_out;

    // workspace layout (bytes)
    char* ws = (char*)d_ws;
    unsigned short* emb_bf  = (unsigned short*)(ws);                    // 30,000,000 B
    unsigned short* hist_bf = (unsigned short*)(ws + 30000000);         // 68,157,440 B
    unsigned short* W5f     = (unsigned short*)(ws + 98157440);         //  1,024,000 B
    float*          bias_all= (float*)(ws + 99181440);                  //      1,280 B
    unsigned short* w1b     = (unsigned short*)(ws + 99182720);         //    196,608 B

    emb_cvt<<<2048, 256, 0, stream>>>(emb, emb_bf, 50000 * DD / 4);
    prep_w<<<(10 * 5 * 20 * 512 + 255) / 256, 256, 0, stream>>>(
        w3, w4, w5, cb3, cb4, cb5, W5f, bias_all, fw1, w1b);
    gather_kernel<<<NB, 512, 0, stream>>>(hist_tok, seg, emb_bf, hist_bf);
    conv_kernel<<<NB / UPB, 768, 0, stream>>>(hist_bf, W5f, bias_all, hist_w, hist_b, out);
    fc_mfma<<<NB / FCM, 256, 0, stream>>>(x, rootidx, w1b, fb1, fw2, fb2, out);
}

// Round 8
// 302.313 us; speedup vs baseline: 1.2222x; 1.1114x over previous
//
#include <hip/hip_runtime.h>

// Problem constants
#define NB    2048     // users / segments
#define NP    16384    // posts
#define LL    50       // tokens per post
#define DD    300      // embedding dim
#define DP    320      // d padded to multiple of 32 (MFMA K tiles)
#define TP    52       // t rows incl. zero pad (48 outputs + 4 shift overhang)
#define NTOT  300      // total filters (100 per conv)
#define NPADF 320      // filters padded to 20 N-tiles of 16
#define INFEAT 768
#define HID2  128
#define UPB   4        // users per conv block
#define FCM   16       // users per fc block

typedef short v8s __attribute__((ext_vector_type(8)));
typedef float v4f __attribute__((ext_vector_type(4)));
typedef float v2f __attribute__((ext_vector_type(2)));
typedef unsigned short v4u __attribute__((ext_vector_type(4)));

__device__ __forceinline__ unsigned short f2bf(float f) {
    union { float f; unsigned u; } v; v.f = f;
    return (unsigned short)((v.u + 0x7FFF + ((v.u >> 16) & 1)) >> 16);  // RNE
}
__device__ __forceinline__ float bf2f(unsigned short u) {
    union { unsigned u; float f; } v; v.u = ((unsigned)u) << 16; return v.f;
}
__device__ __forceinline__ int lower_bound_i(const int* __restrict__ a, int n, int v) {
    int lo = 0, hi = n;
    while (lo < hi) { int mid = (lo + hi) >> 1; if (a[mid] < v) lo = mid + 1; else hi = mid; }
    return lo;
}

// async global->LDS 16B copy: LDS dest = (uniform base) + lane*16 (HW-implicit),
// global src is per-lane. Pass src WITH lane offset, dst WITHOUT.
__device__ __forceinline__ void async_copy16(const void* g, void* l) {
    __builtin_amdgcn_global_load_lds(
        (const __attribute__((address_space(1))) unsigned int*)g,
        (__attribute__((address_space(3))) unsigned int*)l, 16, 0, 0);
}

// ---- fp32 -> fp8 e4m3 (OCP, HW round) for emb table; 4 dims per dword ----
__global__ void emb_cvt8(const float* __restrict__ in, unsigned* __restrict__ out, int n4) {
    for (int i = blockIdx.x * blockDim.x + threadIdx.x; i < n4; i += gridDim.x * blockDim.x) {
        float4 v = ((const float4*)in)[i];
        int o = 0;
        o = __builtin_amdgcn_cvt_pk_fp8_f32(v.x, v.y, o, false);   // bytes 0,1
        o = __builtin_amdgcn_cvt_pk_fp8_f32(v.z, v.w, o, true);    // bytes 2,3
        out[i] = (unsigned)o;
    }
}

// ---- conv weights -> bf16 fragment-order W5f[step=kt*5+s][nt][lane][8] + bias_all
//      + fc_w1 fp32->bf16 (folded in) ----
__global__ void prep_w(const float* __restrict__ w3, const float* __restrict__ w4,
                       const float* __restrict__ w5,
                       const float* __restrict__ b3, const float* __restrict__ b4,
                       const float* __restrict__ b5,
                       unsigned short* __restrict__ W5f, float* __restrict__ bias_all,
                       const float* __restrict__ fw1, unsigned short* __restrict__ w1b) {
    int idx = blockIdx.x * blockDim.x + threadIdx.x;
    if (idx < HID2 * INFEAT / 4) {          // 24576 float4s of fc_w1
        float4 v = ((const float4*)fw1)[idx];
        ushort4 o; o.x = f2bf(v.x); o.y = f2bf(v.y); o.z = f2bf(v.z); o.w = f2bf(v.w);
        ((ushort4*)w1b)[idx] = o;
    }
    if (idx < NPADF) {
        float bv = 0.f;
        if (idx < 100) bv = b3[idx];
        else if (idx < 200) bv = b4[idx - 100];
        else if (idx < 300) bv = b5[idx - 200];
        bias_all[idx] = bv;
    }
    if (idx >= 10 * 5 * 20 * 512) return;
    int j    = idx & 7;
    int lane = (idx >> 3) & 63;
    int rest = idx >> 9;            // kt*100 + s*20 + nt
    int nt = rest % 20;
    int s  = (rest / 20) % 5;
    int kt = rest / 100;
    int col = lane & 15, quad = lane >> 4;
    int nf = nt * 16 + col;
    int d  = kt * 32 + quad * 8 + j;
    float v = 0.f;
    if (nf < NTOT && d < DD) {
        int cls = nf / 100, f = nf % 100, K = cls + 3;
        if (s < K) {
            const float* w = (cls == 0) ? w3 : (cls == 1) ? w4 : w5;
            v = w[(f * DD + d) * K + s];
        }
    }
    W5f[idx] = f2bf(v);
}

// ---- ragged segment-mean -> bf16 hist[b][52][320].
//      FP8 emb table (halves the 491MB logical read stream), HW cvt_pk decode,
//      2-post batched loads + nontemporal hist stores. ----
#define PCHUNK 32
__global__ __launch_bounds__(512, 1) void gather_kernel(
    const int* __restrict__ hist_tokens, const int* __restrict__ seg,
    const unsigned char* __restrict__ emb8, unsigned short* __restrict__ histb)
{
    __shared__ int tokoff[PCHUNK * LL];
    const int b = blockIdx.x, tid = threadIdx.x;
    const int lo = lower_bound_i(seg, NP, b);
    const int hi = lower_bound_i(seg, NP, b + 1);
    const float inv = 1.0f / fmaxf((float)(hi - lo), 1.0f);

    int toff[8], doff[8];
    #pragma unroll
    for (int j = 0; j < 8; ++j) {
        int idx = tid + 512 * j;
        if (idx < 3750) { toff[j] = idx / 75; doff[j] = (idx % 75) * 4; }
        else            { toff[j] = 0;        doff[j] = 0; }
    }
    const bool has8 = (tid < 166);

    float4 acc[8];
    #pragma unroll
    for (int j = 0; j < 8; ++j) acc[j] = make_float4(0.f, 0.f, 0.f, 0.f);

    for (int p0 = lo; p0 < hi; p0 += PCHUNK) {
        const int pc = min(PCHUNK, hi - p0);
        __syncthreads();
        for (int j = tid; j < pc * LL; j += 512)
            tokoff[j] = hist_tokens[p0 * LL + j] * DD;   // byte offset (fp8: 1B/elem)
        __syncthreads();
        int pp = 0;
        for (; pp + 1 < pc; pp += 2) {
            const int* trA = tokoff + pp * LL;
            const int* trB = trA + LL;
            unsigned va[8], vb[8];
            #pragma unroll
            for (int j = 0; j < 7; ++j)
                va[j] = *(const unsigned*)(emb8 + trA[toff[j]] + doff[j]);
            if (has8) va[7] = *(const unsigned*)(emb8 + trA[toff[7]] + doff[7]);
            #pragma unroll
            for (int j = 0; j < 7; ++j)
                vb[j] = *(const unsigned*)(emb8 + trB[toff[j]] + doff[j]);
            if (has8) vb[7] = *(const unsigned*)(emb8 + trB[toff[7]] + doff[7]);
            #pragma unroll
            for (int j = 0; j < 8; ++j) {
                if (j < 7 || has8) {
                    v2f la = __builtin_amdgcn_cvt_pk_f32_fp8(va[j], false);
                    v2f ha = __builtin_amdgcn_cvt_pk_f32_fp8(va[j], true);
                    v2f lb = __builtin_amdgcn_cvt_pk_f32_fp8(vb[j], false);
                    v2f hb2 = __builtin_amdgcn_cvt_pk_f32_fp8(vb[j], true);
                    acc[j].x += la[0] + lb[0];
                    acc[j].y += la[1] + lb[1];
                    acc[j].z += ha[0] + hb2[0];
                    acc[j].w += ha[1] + hb2[1];
                }
            }
        }
        if (pp < pc) {
            const int* tr = tokoff + pp * LL;
            unsigned v[8];
            #pragma unroll
            for (int j = 0; j < 7; ++j)
                v[j] = *(const unsigned*)(emb8 + tr[toff[j]] + doff[j]);
            if (has8) v[7] = *(const unsigned*)(emb8 + tr[toff[7]] + doff[7]);
            #pragma unroll
            for (int j = 0; j < 8; ++j) {
                if (j < 7 || has8) {
                    v2f lv = __builtin_amdgcn_cvt_pk_f32_fp8(v[j], false);
                    v2f hv = __builtin_amdgcn_cvt_pk_f32_fp8(v[j], true);
                    acc[j].x += lv[0]; acc[j].y += lv[1];
                    acc[j].z += hv[0]; acc[j].w += hv[1];
                }
            }
        }
    }

    unsigned short* hb = histb + (size_t)b * TP * DP;
    #pragma unroll
    for (int j = 0; j < 8; ++j) {
        if (j < 7 || has8) {
            v4u o;
            o[0] = f2bf(acc[j].x * inv); o[1] = f2bf(acc[j].y * inv);
            o[2] = f2bf(acc[j].z * inv); o[3] = f2bf(acc[j].w * inv);
            __builtin_nontemporal_store(o, (v4u*)(hb + toff[j] * DP + doff[j]));
        }
    }
    for (int i = tid; i < 640 + 1000; i += 512) {
        int t, d;
        if (i < 640) { t = 50 + i / 320; d = i % 320; }
        else         { int j = i - 640; t = j / 20; d = 300 + j % 20; }
        __builtin_nontemporal_store((unsigned short)0, hb + t * DP + d);
    }
}

// ---- conv: 4 users/block, 12 waves = 4 users x 3 n-groups {0-6,7-13,14-18}.
//      Each wave: all 3 m-tiles x its n-group -> acc[3][7] (84 AGPR), 3 waves/SIMD.
//      PER-KT staging (r6-proven, 92.9us), 2 barriers per kt; compute pure LDS+MFMA.
//      (setprio reverted: r7 showed -2.7us on this barrier-synced structure.) ----
__global__ __launch_bounds__(768, 3) void conv_kernel(
    const unsigned short* __restrict__ histb, const unsigned short* __restrict__ W5f,
    const float* __restrict__ bias_all,
    const float* __restrict__ hist_w, const float* __restrict__ hist_b,
    float* __restrict__ out)
{
    __shared__ __align__(16) unsigned short sA[UPB * 52 * 40];   // 16,640 B
    __shared__ __align__(16) unsigned short sBk[77 * 512];       // 78,848 B
    __shared__ __align__(16) float fpool[UPB * NPADF];           //  5,120 B

    const int b = blockIdx.x, tid = threadIdx.x;
    const int wave = tid >> 6, lane = tid & 63;
    const int col = lane & 15, quad = lane >> 4;
    const int u = wave & 3, g = wave >> 2;      // user 0..3, n-group 0..2
    const int base = (g == 2) ? 14 : g * 7;     // first tile of group
    const int cnt  = (g == 2) ? 5  : 7;         // live tiles in group

    const unsigned short* hbase = histb + (size_t)(b * UPB) * TP * DP;

    // A staging chunk decode (832 chunks: 4 users x 52 rows x 4 ch of 8 shorts)
    const int c0 = tid;
    const int a0_uu = c0 / 208, a0_r = c0 % 208;
    const int a0_row = a0_r >> 2, a0_ch = a0_r & 3;
    const int c1 = tid + 768;
    const int a1_uu = c1 / 208, a1_r = c1 % 208;
    const int a1_row = a1_r >> 2, a1_ch = a1_r & 3;
    const bool hasA1 = (tid < 64);              // 832 - 768

    v4f acc[3][7];
    #pragma unroll
    for (int m = 0; m < 3; ++m)
        #pragma unroll
        for (int j = 0; j < 7; ++j)
            acc[m][j] = (v4f){0.f, 0.f, 0.f, 0.f};

    v8s a0v, a1v;

    // ---- B DMA for one kt: 77 live 1KB tile-chunks, cooperatively by 12 waves ----
    #define STAGE_B(KT)                                                              \
    {                                                                                \
        const unsigned short* wkt = W5f + (size_t)(KT) * 51200;                      \
        _Pragma("unroll")                                                            \
        for (int s5 = 0; s5 < 5; ++s5) {                                             \
            const int Ls  = (s5 < 3) ? 19 : (s5 == 3 ? 13 : 7);                      \
            const int los = (s5 < 3) ? 0  : (s5 == 3 ? 6  : 12);                     \
            const int cbs = (s5 < 3) ? 19 * s5 : (s5 == 3 ? 57 : 70);                \
            const unsigned short* srcs = wkt + s5 * 10240 + los * 512 + lane * 8;    \
            unsigned short* dsts = sBk + cbs * 512;                                  \
            if (wave < Ls)                                                           \
                async_copy16(srcs + wave * 512, dsts + wave * 512);                  \
            if (wave + 12 < Ls)                                                      \
                async_copy16(srcs + (wave + 12) * 512, dsts + (wave + 12) * 512);    \
        }                                                                            \
    }

    // ---- prologue: stage kt=0 (A regs -> ds_write; B DMA), one barrier ----
    a0v = *(const v8s*)(hbase + (size_t)a0_uu * TP * DP + a0_row * DP + a0_ch * 8);
    if (hasA1)
        a1v = *(const v8s*)(hbase + (size_t)a1_uu * TP * DP + a1_row * DP + a1_ch * 8);
    STAGE_B(0);
    *(v8s*)(sA + (a0_uu * 52 + a0_row) * 40 + a0_ch * 8) = a0v;
    if (hasA1) *(v8s*)(sA + (a1_uu * 52 + a1_row) * 40 + a1_ch * 8) = a1v;
    __syncthreads();    // drains DMA + A writes; everything visible

    for (int kt = 0; kt < 10; ++kt) {
        // issue next kt's A reg-loads early (pure VGPR, overlaps compute)
        if (kt < 9) {
            const int ko = (kt + 1) * 32;
            a0v = *(const v8s*)(hbase + (size_t)a0_uu * TP * DP + a0_row * DP + ko + a0_ch * 8);
            if (hasA1)
                a1v = *(const v8s*)(hbase + (size_t)a1_uu * TP * DP + a1_row * DP + ko + a1_ch * 8);
        }

        // ---- compute: 5 steps, pure LDS + MFMA ----
        #pragma unroll
        for (int s = 0; s < 5; ++s) {
            const int lo  = (s == 3) ? 6 : (s == 4) ? 12 : 0;
            const int cbs = (s < 3) ? 19 * s : (s == 3 ? 57 : 70);

            const unsigned short* Arow = sA + (u * 52 + col + s) * 40 + quad * 8;
            const v8s am0 = *(const v8s*)(Arow);
            const v8s am1 = *(const v8s*)(Arow + 640);    // +16 rows * 40
            const v8s am2 = *(const v8s*)(Arow + 1280);   // +32 rows * 40
            #pragma unroll
            for (int j = 0; j < 7; ++j) {
                const int t = base + j;
                if (j < cnt && t >= lo) {
                    const int blk = cbs + (t - lo);
                    const v8s bf = *(const v8s*)(sBk + blk * 512 + lane * 8);
                    acc[0][j] = __builtin_amdgcn_mfma_f32_16x16x32_bf16(am0, bf, acc[0][j], 0, 0, 0);
                    acc[1][j] = __builtin_amdgcn_mfma_f32_16x16x32_bf16(am1, bf, acc[1][j], 0, 0, 0);
                    acc[2][j] = __builtin_amdgcn_mfma_f32_16x16x32_bf16(am2, bf, acc[2][j], 0, 0, 0);
                }
            }
        }

        // ---- stage kt+1 in a clean 2-barrier window ----
        if (kt < 9) {
            __syncthreads();               // bar1: all reads of sA/sBk done
            STAGE_B(kt + 1);
            *(v8s*)(sA + (a0_uu * 52 + a0_row) * 40 + a0_ch * 8) = a0v;
            if (hasA1) *(v8s*)(sA + (a1_uu * 52 + a1_row) * 40 + a1_ch * 8) = a1v;
            __syncthreads();               // bar2: vmcnt(0) drain -> staged visible
        }
    }
    #undef STAGE_B

    // maxpool + bias + relu -> fpool (wave-local: each wave owns all m for its tiles)
    #pragma unroll
    for (int j = 0; j < 7; ++j) {
        if (j < cnt) {
            const int nf = (base + j) * 16 + col;
            const int Tout = 48 - nf / 100;        // 48/47/46 per class
            float mx = -1e30f;
            #pragma unroll
            for (int m = 0; m < 3; ++m)
                #pragma unroll
                for (int r = 0; r < 4; ++r) {
                    const int t = m * 16 + quad * 4 + r;
                    if (t < Tout) mx = fmaxf(mx, acc[m][j][r]);
                }
            mx = fmaxf(mx, __shfl_xor(mx, 16, 64));
            mx = fmaxf(mx, __shfl_xor(mx, 32, 64));
            if (quad == 0 && nf < NTOT)
                fpool[u * NPADF + nf] = fmaxf(0.f, mx + bias_all[nf]);
        }
    }
    __syncthreads();

    // rec = fpool @ hist_w.T + hist_b
    if (tid < UPB * 64) {
        const int uu = tid >> 6, o = tid & 63;
        const float4* fw = (const float4*)(hist_w + o * NTOT);
        const float4* fp = (const float4*)(fpool + uu * NPADF);
        float sum = 0.f;
        #pragma unroll
        for (int q = 0; q < NTOT / 4; ++q) {
            float4 aa = fp[q], ww = fw[q];
            sum += aa.x * ww.x + aa.y * ww.y + aa.z * ww.z + aa.w * ww.w;
        }
        out[(b * UPB + uu) * 64 + o] = sum + hist_b[o];
    }
}

// ---- fc via MFMA: h = relu(x[root] @ w1b.T + b1) ; out += h @ w2.T + b2 ----
__global__ __launch_bounds__(256, 1) void fc_mfma(
    const float* __restrict__ x, const int* __restrict__ rootindex,
    const unsigned short* __restrict__ w1b, const float* __restrict__ b1,
    const float* __restrict__ w2, const float* __restrict__ b2,
    float* __restrict__ out)
{
    __shared__ __align__(16) unsigned short sA[FCM * 72];   // 16 rows x 64k (pad 72)
    __shared__ __align__(16) float hl[FCM * 132];           // h tile, stride 132
    __shared__ __align__(16) float w2l[64 * 129];           // w2 staged, stride 129
    __shared__ int roots[FCM];

    const int b = blockIdx.x, tid = threadIdx.x;
    if (tid < FCM) roots[tid] = rootindex[b * FCM + tid];
    for (int i = tid; i < 64 * HID2; i += 256)
        w2l[(i >> 7) * 129 + (i & 127)] = w2[i];
    __syncthreads();

    const int wave = tid >> 6, lane = tid & 63;
    const int col = lane & 15, quad = lane >> 4;

    v4f acc[2];
    acc[0] = (v4f){0.f, 0.f, 0.f, 0.f};
    acc[1] = (v4f){0.f, 0.f, 0.f, 0.f};

    const int r_st = tid >> 4, q_st = tid & 15;

    for (int kt = 0; kt < 12; ++kt) {
        __syncthreads();
        float4 v = *(const float4*)(x + (size_t)roots[r_st] * INFEAT + kt * 64 + q_st * 4);
        ushort4 o; o.x = f2bf(v.x); o.y = f2bf(v.y); o.z = f2bf(v.z); o.w = f2bf(v.w);
        *(ushort4*)(sA + r_st * 72 + q_st * 4) = o;
        __syncthreads();
        #pragma unroll
        for (int kc = 0; kc < 2; ++kc) {
            const v8s a = *(const v8s*)(sA + col * 72 + kc * 32 + quad * 8);
            #pragma unroll
            for (int n = 0; n < 2; ++n) {
                const int nf = (wave * 2 + n) * 16 + col;
                const v8s bfr = *(const v8s*)(w1b + (size_t)nf * INFEAT + kt * 64 + kc * 32 + quad * 8);
                acc[n] = __builtin_amdgcn_mfma_f32_16x16x32_bf16(a, bfr, acc[n], 0, 0, 0);
            }
        }
    }

    #pragma unroll
    for (int nt = 0; nt < 2; ++nt) {
        const int n = (wave * 2 + nt) * 16 + col;
        const float bv = b1[n];
        #pragma unroll
        for (int r = 0; r < 4; ++r)
            hl[(quad * 4 + r) * 132 + n] = fmaxf(acc[nt][r] + bv, 0.f);
    }
    __syncthreads();

    {
        const int o = tid & 63, ug = tid >> 6;
        const float b2v = b2[o];
        const float* wrow = w2l + o * 129;
        #pragma unroll
        for (int i = 0; i < 4; ++i) {
            const int u = ug * 4 + i;
            const float* hrow = hl + u * 132;
            float s = 0.f;
            #pragma unroll 16
            for (int k = 0; k < HID2; ++k) s += hrow[k] * wrow[k];
            out[(b * FCM + u) * 64 + o] += s + b2v;
        }
    }
}

extern "C" void kernel_launch(void* const* d_in, const int* in_sizes, int n_in,
                              void* d_out, int out_size, void* d_ws, size_t ws_size,
                              hipStream_t stream) {
    const float* x        = (const float*)d_in[0];
    const int*   rootidx  = (const int*)d_in[1];
    const int*   hist_tok = (const int*)d_in[2];
    const int*   seg      = (const int*)d_in[3];
    const float* emb      = (const float*)d_in[4];
    const float* w3       = (const float*)d_in[5];
    const float* cb3      = (const float*)d_in[6];
    const float* w4       = (const float*)d_in[7];
    const float* cb4      = (const float*)d_in[8];
    const float* w5       = (const float*)d_in[9];
    const float* cb5      = (const float*)d_in[10];
    const float* hist_w   = (const float*)d_in[11];
    const float* hist_b   = (const float*)d_in[12];
    const float* fw1      = (const float*)d_in[13];
    const float* fb1      = (const float*)d_in[14];
    const float* fw2      = (const float*)d_in[15];
    const float* fb2      = (const float*)d_in[16];
    float* out = (float*)d_out;

    // workspace layout (bytes)
    char* ws = (char*)d_ws;
    unsigned char*  emb8    = (unsigned char*)(ws);                     // 15,000,000 B (fp8)
    unsigned short* hist_bf = (unsigned short*)(ws + 30000000);         // 68,157,440 B
    unsigned short* W5f     = (unsigned short*)(ws + 98157440);         //  1,024,000 B
    float*          bias_all= (float*)(ws + 99181440);                  //      1,280 B
    unsigned short* w1b     = (unsigned short*)(ws + 99182720);         //    196,608 B

    emb_cvt8<<<2048, 256, 0, stream>>>(emb, (unsigned*)emb8, 50000 * DD / 4);
    prep_w<<<(10 * 5 * 20 * 512 + 255) / 256, 256, 0, stream>>>(
        w3, w4, w5, cb3, cb4, cb5, W5f, bias_all, fw1, w1b);
    gather_kernel<<<NB, 512, 0, stream>>>(hist_tok, seg, emb8, hist_bf);
    conv_kernel<<<NB / UPB, 768, 0, stream>>>(hist_bf, W5f, bias_all, hist_w, hist_b, out);
    fc_mfma<<<NB / FCM, 256, 0, stream>>>(x, rootidx, w1b, fb1, fw2, fb2, out);
}

// Round 9
// 282.806 us; speedup vs baseline: 1.3065x; 1.0690x over previous
//
#include <hip/hip_runtime.h>

// Problem constants
#define NB    2048     // users / segments
#define NP    16384    // posts
#define LL    50       // tokens per post
#define DD    300      // embedding dim
#define TP    52       // t rows incl. zero pad (48 outputs + 4 shift overhang)
#define NTOT  300      // total filters (100 per conv)
#define NPADF 320      // filters padded to 20 N-tiles of 16
#define INFEAT 768
#define HID2  128
#define UPB   4        // users per conv block
#define FCM   16       // users per fc block
#define BKT   39936    // per-kt B block bytes (78 tiles x 512B; 77 live + 1 pad)

typedef short v8s __attribute__((ext_vector_type(8)));
typedef float v4f __attribute__((ext_vector_type(4)));
typedef float v2f __attribute__((ext_vector_type(2)));

__device__ __forceinline__ unsigned short f2bf(float f) {
    union { float f; unsigned u; } v; v.f = f;
    return (unsigned short)((v.u + 0x7FFF + ((v.u >> 16) & 1)) >> 16);  // RNE
}
__device__ __forceinline__ int lower_bound_i(const int* __restrict__ a, int n, int v) {
    int lo = 0, hi = n;
    while (lo < hi) { int mid = (lo + hi) >> 1; if (a[mid] < v) lo = mid + 1; else hi = mid; }
    return lo;
}

// async global->LDS 16B copy: LDS dest = (uniform base) + lane*16 (HW-implicit),
// global src is per-lane. Pass src WITH lane offset, dst WITHOUT.
__device__ __forceinline__ void async_copy16(const void* g, void* l) {
    __builtin_amdgcn_global_load_lds(
        (const __attribute__((address_space(1))) unsigned int*)g,
        (__attribute__((address_space(3))) unsigned int*)l, 16, 0, 0);
}

// ---- fp32 -> fp8 e4m3 (OCP, HW round) for emb table; 4 dims per dword ----
__global__ void emb_cvt8(const float* __restrict__ in, unsigned* __restrict__ out, int n4) {
    for (int i = blockIdx.x * blockDim.x + threadIdx.x; i < n4; i += gridDim.x * blockDim.x) {
        float4 v = ((const float4*)in)[i];
        int o = 0;
        o = __builtin_amdgcn_cvt_pk_fp8_f32(v.x, v.y, o, false);   // bytes 0,1
        o = __builtin_amdgcn_cvt_pk_fp8_f32(v.z, v.w, o, true);    // bytes 2,3
        out[i] = (unsigned)o;
    }
}

// ---- conv weights -> fp8 (x16 scale) compacted fragment order
//      W5f8[kt][cbs(s)+nt-lo_s][lane][8B] + bias_all + fc_w1 bf16 ----
__global__ void prep_w8(const float* __restrict__ w3, const float* __restrict__ w4,
                        const float* __restrict__ w5,
                        const float* __restrict__ b3, const float* __restrict__ b4,
                        const float* __restrict__ b5,
                        unsigned char* __restrict__ W5f8, float* __restrict__ bias_all,
                        const float* __restrict__ fw1, unsigned short* __restrict__ w1b) {
    const int idx = blockIdx.x * blockDim.x + threadIdx.x;
    if (idx < HID2 * INFEAT / 4) {          // fc_w1 -> bf16
        float4 v = ((const float4*)fw1)[idx];
        ushort4 o; o.x = f2bf(v.x); o.y = f2bf(v.y); o.z = f2bf(v.z); o.w = f2bf(v.w);
        ((ushort4*)w1b)[idx] = o;
    }
    if (idx < NPADF) {
        float bv = 0.f;
        if (idx < 100) bv = b3[idx];
        else if (idx < 200) bv = b4[idx - 100];
        else if (idx < 300) bv = b5[idx - 200];
        bias_all[idx] = bv;
    }
    if (idx < 10 * 128)                     // zero the 512B pad tile per kt
        *(unsigned*)(W5f8 + (size_t)(idx >> 7) * BKT + 39424 + (idx & 127) * 4) = 0u;
    if (idx >= 256000) return;              // 10 kt x 5 s x 20 nt x 64 lane x 4 j2
    const int j2   = idx & 3;
    const int lane = (idx >> 2) & 63;
    const int rest = idx >> 8;              // kt*100 + s*20 + nt
    const int nt = rest % 20;
    const int s  = (rest / 20) % 5;
    const int kt = rest / 100;
    const int lo = (s == 3) ? 6 : (s == 4) ? 12 : 0;
    if (nt < lo || nt >= 19) return;        // dead tile (tap-skip / pad filters)
    const int cbs = (s < 3) ? 19 * s : (s == 3 ? 57 : 70);
    const int col = lane & 15, quad = lane >> 4;
    const int nf = nt * 16 + col;
    float v0 = 0.f, v1 = 0.f;
    if (nf < NTOT) {
        const int cls = nf / 100, f = nf % 100, K = cls + 3;
        if (s < K) {
            const float* w = (cls == 0) ? w3 : (cls == 1) ? w4 : w5;
            const int d0 = kt * 32 + quad * 8 + j2 * 2;
            if (d0 < DD)     v0 = 16.f * w[(f * DD + d0) * K + s];
            if (d0 + 1 < DD) v1 = 16.f * w[(f * DD + d0 + 1) * K + s];
        }
    }
    const int p = __builtin_amdgcn_cvt_pk_fp8_f32(v0, v1, 0, false);
    *(unsigned short*)(W5f8 + (size_t)kt * BKT + (cbs + nt - lo) * 512 + lane * 8 + j2 * 2)
        = (unsigned short)(p & 0xffff);
}

// ---- ragged segment-mean -> fp8 (x16 scale) hist[b][52][320B].
//      FP8 emb reads, 2-post batching, nontemporal fp8 stores. ----
#define PCHUNK 32
__global__ __launch_bounds__(512, 1) void gather_kernel(
    const int* __restrict__ hist_tokens, const int* __restrict__ seg,
    const unsigned char* __restrict__ emb8, unsigned char* __restrict__ hist8)
{
    __shared__ int tokoff[PCHUNK * LL];
    const int b = blockIdx.x, tid = threadIdx.x;
    const int lo = lower_bound_i(seg, NP, b);
    const int hi = lower_bound_i(seg, NP, b + 1);
    const float inv16 = 16.f / fmaxf((float)(hi - lo), 1.0f);

    int toff[8], doff[8];
    #pragma unroll
    for (int j = 0; j < 8; ++j) {
        int idx = tid + 512 * j;
        if (idx < 3750) { toff[j] = idx / 75; doff[j] = (idx % 75) * 4; }
        else            { toff[j] = 0;        doff[j] = 0; }
    }
    const bool has8 = (tid < 166);

    float4 acc[8];
    #pragma unroll
    for (int j = 0; j < 8; ++j) acc[j] = make_float4(0.f, 0.f, 0.f, 0.f);

    for (int p0 = lo; p0 < hi; p0 += PCHUNK) {
        const int pc = min(PCHUNK, hi - p0);
        __syncthreads();
        for (int j = tid; j < pc * LL; j += 512)
            tokoff[j] = hist_tokens[p0 * LL + j] * DD;   // byte offset (1B/dim)
        __syncthreads();
        int pp = 0;
        for (; pp + 1 < pc; pp += 2) {
            const int* trA = tokoff + pp * LL;
            const int* trB = trA + LL;
            unsigned va[8], vb[8];
            #pragma unroll
            for (int j = 0; j < 7; ++j)
                va[j] = *(const unsigned*)(emb8 + trA[toff[j]] + doff[j]);
            if (has8) va[7] = *(const unsigned*)(emb8 + trA[toff[7]] + doff[7]);
            #pragma unroll
            for (int j = 0; j < 7; ++j)
                vb[j] = *(const unsigned*)(emb8 + trB[toff[j]] + doff[j]);
            if (has8) vb[7] = *(const unsigned*)(emb8 + trB[toff[7]] + doff[7]);
            #pragma unroll
            for (int j = 0; j < 8; ++j) {
                if (j < 7 || has8) {
                    v2f la = __builtin_amdgcn_cvt_pk_f32_fp8(va[j], false);
                    v2f ha = __builtin_amdgcn_cvt_pk_f32_fp8(va[j], true);
                    v2f lb = __builtin_amdgcn_cvt_pk_f32_fp8(vb[j], false);
                    v2f hb2 = __builtin_amdgcn_cvt_pk_f32_fp8(vb[j], true);
                    acc[j].x += la[0] + lb[0];
                    acc[j].y += la[1] + lb[1];
                    acc[j].z += ha[0] + hb2[0];
                    acc[j].w += ha[1] + hb2[1];
                }
            }
        }
        if (pp < pc) {
            const int* tr = tokoff + pp * LL;
            unsigned v[8];
            #pragma unroll
            for (int j = 0; j < 7; ++j)
                v[j] = *(const unsigned*)(emb8 + tr[toff[j]] + doff[j]);
            if (has8) v[7] = *(const unsigned*)(emb8 + tr[toff[7]] + doff[7]);
            #pragma unroll
            for (int j = 0; j < 8; ++j) {
                if (j < 7 || has8) {
                    v2f lv = __builtin_amdgcn_cvt_pk_f32_fp8(v[j], false);
                    v2f hv = __builtin_amdgcn_cvt_pk_f32_fp8(v[j], true);
                    acc[j].x += lv[0]; acc[j].y += lv[1];
                    acc[j].z += hv[0]; acc[j].w += hv[1];
                }
            }
        }
    }

    unsigned char* hb = hist8 + (size_t)b * TP * 320;
    #pragma unroll
    for (int j = 0; j < 8; ++j) {
        if (j < 7 || has8) {
            int p = 0;
            p = __builtin_amdgcn_cvt_pk_fp8_f32(acc[j].x * inv16, acc[j].y * inv16, p, false);
            p = __builtin_amdgcn_cvt_pk_fp8_f32(acc[j].z * inv16, acc[j].w * inv16, p, true);
            __builtin_nontemporal_store((unsigned)p, (unsigned*)(hb + toff[j] * 320 + doff[j]));
        }
    }
    // zero-fill: rows 50-51 (160 dwords) + d in [300,320) for t<50 (250 dwords)
    for (int i = tid; i < 410; i += 512) {
        unsigned char* p;
        if (i < 160) { const int t = 50 + i / 80; p = hb + t * 320 + (i % 80) * 4; }
        else         { const int j = i - 160; p = hb + (j / 5) * 320 + 300 + (j % 5) * 4; }
        __builtin_nontemporal_store(0u, (unsigned*)p);
    }
}

// ---- conv (FP8): 4 users/block, 12 waves = 4 users x 3 n-groups {0-6,7-13,14-18}.
//      Each wave: 3 m-tiles x its n-group -> acc[3][7] (84 AGPR), 3 waves/SIMD.
//      mfma_f32_16x16x32_fp8_fp8: same shape/rate as bf16, HALF the operand bytes
//      -> ds_read_b64, half staging. Inputs pre-scaled x16 (acc /256 at epilogue).
//      Fully double-buffered (sA[2], sB[2], 102KB LDS), ONE barrier per kt:
//        iter kt: issue DMA B(kt+1)->sB[^1]; ds_write A(kt+1)->sA[^1];
//                 preload A(kt+2) regs; compute(kt) from [cur]; barrier.
//      All cross-buffer hazards are separated by that barrier; each wave's DMA
//      is drained by the barrier's vmcnt(0) AFTER the ~4K-cyc compute -> hidden.
//      sched_barrier(0) pins the staging issues above the compute batch. ----
__global__ __launch_bounds__(768, 3) void conv_kernel(
    const unsigned char* __restrict__ histb, const unsigned char* __restrict__ W5f8,
    const float* __restrict__ bias_all,
    const float* __restrict__ hist_w, const float* __restrict__ hist_b,
    float* __restrict__ out)
{
    __shared__ __align__(16) unsigned char sA[2][208 * 40];     // 2 x 8,320 B
    __shared__ __align__(16) unsigned char sB[2][BKT];          // 2 x 39,936 B
    __shared__ __align__(16) float fpool[UPB * NPADF];          // 5,120 B

    const int b = blockIdx.x, tid = threadIdx.x;
    const int wave = tid >> 6, lane = tid & 63;
    const int col = lane & 15, quad = lane >> 4;
    const int u = wave & 3, g = wave >> 2;      // user 0..3, n-group 0..2
    const int base = (g == 2) ? 14 : g * 7;     // first tile of group
    const int cnt  = (g == 2) ? 5  : 7;         // live tiles in group

    const unsigned char* hbase = histb + (size_t)(b * UPB) * TP * 320;

    // A staging: 832 chunks of 8B = 208 rows x 4 ch
    const int r0 = tid >> 2, ch0 = tid & 3;
    const int r1 = (tid + 768) >> 2;            // ch1 == ch0 (768%4==0)
    const bool hasA1 = (tid < 64);

    v4f acc[3][7];
    #pragma unroll
    for (int m = 0; m < 3; ++m)
        #pragma unroll
        for (int j = 0; j < 7; ++j)
            acc[m][j] = (v4f){0.f, 0.f, 0.f, 0.f};

    unsigned long long a0v, a1v = 0;

    // 39 x 1KB DMA chunks per kt (78 tiles x 512B), cooperatively by 12 waves
    #define STAGE_B8(KT, BUF)                                                      \
    {                                                                              \
        const unsigned char* _src = W5f8 + (size_t)(KT) * BKT + lane * 16;         \
        unsigned char* _dst = sB[BUF];                                             \
        async_copy16(_src + wave * 1024,        _dst + wave * 1024);               \
        async_copy16(_src + (wave + 12) * 1024, _dst + (wave + 12) * 1024);        \
        async_copy16(_src + (wave + 24) * 1024, _dst + (wave + 24) * 1024);        \
        if (wave < 3)                                                              \
            async_copy16(_src + (wave + 36) * 1024, _dst + (wave + 36) * 1024);    \
    }

    // ---- prologue: stage kt=0 into buffers[0] ----
    a0v = *(const unsigned long long*)(hbase + r0 * 320 + ch0 * 8);
    if (hasA1) a1v = *(const unsigned long long*)(hbase + r1 * 320 + ch0 * 8);
    STAGE_B8(0, 0);
    *(unsigned long long*)(sA[0] + r0 * 40 + ch0 * 8) = a0v;
    if (hasA1) *(unsigned long long*)(sA[0] + r1 * 40 + ch0 * 8) = a1v;
    __syncthreads();    // drains DMA + A writes
    // preload A(1) regs
    a0v = *(const unsigned long long*)(hbase + r0 * 320 + 32 + ch0 * 8);
    if (hasA1) a1v = *(const unsigned long long*)(hbase + r1 * 320 + 32 + ch0 * 8);

    for (int kt = 0; kt < 10; ++kt) {
        const int cur = kt & 1;
        // -- stage kt+1 into the other buffers (issued EARLY, hidden under compute) --
        if (kt < 9) {
            STAGE_B8(kt + 1, cur ^ 1);
            *(unsigned long long*)(sA[cur ^ 1] + r0 * 40 + ch0 * 8) = a0v;
            if (hasA1) *(unsigned long long*)(sA[cur ^ 1] + r1 * 40 + ch0 * 8) = a1v;
            if (kt < 8) {
                const int ko = (kt + 2) * 32;
                a0v = *(const unsigned long long*)(hbase + r0 * 320 + ko + ch0 * 8);
                if (hasA1) a1v = *(const unsigned long long*)(hbase + r1 * 320 + ko + ch0 * 8);
            }
        }
        __builtin_amdgcn_sched_barrier(0);   // keep staging issues above compute

        // ---- compute: 5 steps, pure LDS + MFMA from buffers[cur] ----
        #pragma unroll
        for (int s = 0; s < 5; ++s) {
            const int lo  = (s == 3) ? 6 : (s == 4) ? 12 : 0;
            const int cbs = (s < 3) ? 19 * s : (s == 3 ? 57 : 70);
            const unsigned char* Ab = sA[cur] + (u * 52 + col + s) * 40 + quad * 8;
            const long am0 = *(const long*)(Ab);
            const long am1 = *(const long*)(Ab + 640);     // +16 rows * 40B
            const long am2 = *(const long*)(Ab + 1280);    // +32 rows * 40B
            #pragma unroll
            for (int j = 0; j < 7; ++j) {
                const int t = base + j;
                if (j < cnt && t >= lo) {
                    const long bf = *(const long*)(sB[cur] + (cbs + t - lo) * 512 + lane * 8);
                    acc[0][j] = __builtin_amdgcn_mfma_f32_16x16x32_fp8_fp8(am0, bf, acc[0][j], 0, 0, 0);
                    acc[1][j] = __builtin_amdgcn_mfma_f32_16x16x32_fp8_fp8(am1, bf, acc[1][j], 0, 0, 0);
                    acc[2][j] = __builtin_amdgcn_mfma_f32_16x16x32_fp8_fp8(am2, bf, acc[2][j], 0, 0, 0);
                }
            }
        }
        if (kt < 9) __syncthreads();   // drains this iter's DMA; frees [cur] for kt+1 staging
    }
    #undef STAGE_B8

    // maxpool + unscale (x16*x16 inputs -> /256) + bias + relu -> fpool
    #pragma unroll
    for (int j = 0; j < 7; ++j) {
        if (j < cnt) {
            const int nf = (base + j) * 16 + col;
            const int Tout = 48 - nf / 100;        // 48/47/46 per class
            float mx = -1e30f;
            #pragma unroll
            for (int m = 0; m < 3; ++m)
                #pragma unroll
                for (int r = 0; r < 4; ++r) {
                    const int t = m * 16 + quad * 4 + r;
                    if (t < Tout) mx = fmaxf(mx, acc[m][j][r]);
                }
            mx = fmaxf(mx, __shfl_xor(mx, 16, 64));
            mx = fmaxf(mx, __shfl_xor(mx, 32, 64));
            if (quad == 0 && nf < NTOT)
                fpool[u * NPADF + nf] = fmaxf(0.f, mx * (1.f / 256.f) + bias_all[nf]);
        }
    }
    __syncthreads();

    // rec = fpool @ hist_w.T + hist_b
    if (tid < UPB * 64) {
        const int uu = tid >> 6, o = tid & 63;
        const float4* fw = (const float4*)(hist_w + o * NTOT);
        const float4* fp = (const float4*)(fpool + uu * NPADF);
        float sum = 0.f;
        #pragma unroll
        for (int q = 0; q < NTOT / 4; ++q) {
            float4 aa = fp[q], ww = fw[q];
            sum += aa.x * ww.x + aa.y * ww.y + aa.z * ww.z + aa.w * ww.w;
        }
        out[(b * UPB + uu) * 64 + o] = sum + hist_b[o];
    }
}

// ---- fc via MFMA: h = relu(x[root] @ w1b.T + b1) ; out += h @ w2.T + b2 ----
__global__ __launch_bounds__(256, 1) void fc_mfma(
    const float* __restrict__ x, const int* __restrict__ rootindex,
    const unsigned short* __restrict__ w1b, const float* __restrict__ b1,
    const float* __restrict__ w2, const float* __restrict__ b2,
    float* __restrict__ out)
{
    __shared__ __align__(16) unsigned short sA[FCM * 72];   // 16 rows x 64k (pad 72)
    __shared__ __align__(16) float hl[FCM * 132];           // h tile, stride 132
    __shared__ __align__(16) float w2l[64 * 129];           // w2 staged, stride 129
    __shared__ int roots[FCM];

    const int b = blockIdx.x, tid = threadIdx.x;
    if (tid < FCM) roots[tid] = rootindex[b * FCM + tid];
    for (int i = tid; i < 64 * HID2; i += 256)
        w2l[(i >> 7) * 129 + (i & 127)] = w2[i];
    __syncthreads();

    const int wave = tid >> 6, lane = tid & 63;
    const int col = lane & 15, quad = lane >> 4;

    v4f acc[2];
    acc[0] = (v4f){0.f, 0.f, 0.f, 0.f};
    acc[1] = (v4f){0.f, 0.f, 0.f, 0.f};

    const int r_st = tid >> 4, q_st = tid & 15;

    for (int kt = 0; kt < 12; ++kt) {
        __syncthreads();
        float4 v = *(const float4*)(x + (size_t)roots[r_st] * INFEAT + kt * 64 + q_st * 4);
        ushort4 o; o.x = f2bf(v.x); o.y = f2bf(v.y); o.z = f2bf(v.z); o.w = f2bf(v.w);
        *(ushort4*)(sA + r_st * 72 + q_st * 4) = o;
        __syncthreads();
        #pragma unroll
        for (int kc = 0; kc < 2; ++kc) {
            const v8s a = *(const v8s*)(sA + col * 72 + kc * 32 + quad * 8);
            #pragma unroll
            for (int n = 0; n < 2; ++n) {
                const int nf = (wave * 2 + n) * 16 + col;
                const v8s bfr = *(const v8s*)(w1b + (size_t)nf * INFEAT + kt * 64 + kc * 32 + quad * 8);
                acc[n] = __builtin_amdgcn_mfma_f32_16x16x32_bf16(a, bfr, acc[n], 0, 0, 0);
            }
        }
    }

    #pragma unroll
    for (int nt = 0; nt < 2; ++nt) {
        const int n = (wave * 2 + nt) * 16 + col;
        const float bv = b1[n];
        #pragma unroll
        for (int r = 0; r < 4; ++r)
            hl[(quad * 4 + r) * 132 + n] = fmaxf(acc[nt][r] + bv, 0.f);
    }
    __syncthreads();

    {
        const int o = tid & 63, ug = tid >> 6;
        const float b2v = b2[o];
        const float* wrow = w2l + o * 129;
        #pragma unroll
        for (int i = 0; i < 4; ++i) {
            const int u = ug * 4 + i;
            const float* hrow = hl + u * 132;
            float s = 0.f;
            #pragma unroll 16
            for (int k = 0; k < HID2; ++k) s += hrow[k] * wrow[k];
            out[(b * FCM + u) * 64 + o] += s + b2v;
        }
    }
}

extern "C" void kernel_launch(void* const* d_in, const int* in_sizes, int n_in,
                              void* d_out, int out_size, void* d_ws, size_t ws_size,
                              hipStream_t stream) {
    const float* x        = (const float*)d_in[0];
    const int*   rootidx  = (const int*)d_in[1];
    const int*   hist_tok = (const int*)d_in[2];
    const int*   seg      = (const int*)d_in[3];
    const float* emb      = (const float*)d_in[4];
    const float* w3       = (const float*)d_in[5];
    const float* cb3      = (const float*)d_in[6];
    const float* w4       = (const float*)d_in[7];
    const float* cb4      = (const float*)d_in[8];
    const float* w5       = (const float*)d_in[9];
    const float* cb5      = (const float*)d_in[10];
    const float* hist_w   = (const float*)d_in[11];
    const float* hist_b   = (const float*)d_in[12];
    const float* fw1      = (const float*)d_in[13];
    const float* fb1      = (const float*)d_in[14];
    const float* fw2      = (const float*)d_in[15];
    const float* fb2      = (const float*)d_in[16];
    float* out = (float*)d_out;

    // workspace layout (bytes)
    char* ws = (char*)d_ws;
    unsigned char*  emb8    = (unsigned char*)(ws);                     // 15,000,000 B (fp8)
    unsigned char*  hist8   = (unsigned char*)(ws + 30000000);          // 34,078,720 B (fp8 x16)
    unsigned char*  W5f8    = (unsigned char*)(ws + 98157440);          //    399,360 B (fp8 x16)
    float*          bias_all= (float*)(ws + 99181440);                  //      1,280 B
    unsigned short* w1b     = (unsigned short*)(ws + 99182720);         //    196,608 B

    emb_cvt8<<<2048, 256, 0, stream>>>(emb, (unsigned*)emb8, 50000 * DD / 4);
    prep_w8<<<1000, 256, 0, stream>>>(
        w3, w4, w5, cb3, cb4, cb5, W5f8, bias_all, fw1, w1b);
    gather_kernel<<<NB, 512, 0, stream>>>(hist_tok, seg, emb8, hist8);
    conv_kernel<<<NB / UPB, 768, 0, stream>>>(hist8, W5f8, bias_all, hist_w, hist_b, out);
    fc_mfma<<<NB / FCM, 256, 0, stream>>>(x, rootidx, w1b, fb1, fw2, fb2, out);
}